// Round 1
// baseline (421.617 us; speedup 1.0000x reference)
//
#include <hip/hip_runtime.h>
#include <hip/hip_bf16.h>
#include <stdint.h>

#define DMODEL 1024
#define NH 16
#define DKH 64
#define BB 2
#define SS 2048
#define MTOT (BB*SS)   // 4096

#define BM 128
#define BN 128
#define BK 32

using f32x4  = __attribute__((ext_vector_type(4))) float;
using bf16x8 = __attribute__((ext_vector_type(8))) __bf16;

// async global->LDS, 16B per lane. LDS dest must be wave-uniform base + lane*16.
#define GLL(g, l) __builtin_amdgcn_global_load_lds( \
    (const __attribute__((address_space(1))) unsigned int*)(g), \
    (__attribute__((address_space(3))) unsigned int*)(l), 16, 0, 0)

__device__ __forceinline__ unsigned short f2bf(float f) {
  union { float f; uint32_t u; } v; v.f = f;
  uint32_t r = v.u + 0x7FFFu + ((v.u >> 16) & 1u);
  return (unsigned short)(r >> 16);
}

__global__ __launch_bounds__(256) void cvt_bf16(const float* __restrict__ src,
                                                unsigned short* __restrict__ dst, int n8) {
  int i = blockIdx.x * blockDim.x + threadIdx.x;
  if (i >= n8) return;
  const float4* s4 = (const float4*)src;
  float4 a = s4[2*i], b = s4[2*i+1];
  uint4 o;
  o.x = (uint32_t)f2bf(a.x) | ((uint32_t)f2bf(a.y) << 16);
  o.y = (uint32_t)f2bf(a.z) | ((uint32_t)f2bf(a.w) << 16);
  o.z = (uint32_t)f2bf(b.x) | ((uint32_t)f2bf(b.y) << 16);
  o.w = (uint32_t)f2bf(b.z) | ((uint32_t)f2bf(b.w) << 16);
  *(uint4*)(dst + (size_t)i * 8) = o;
}

// ---- shared 128x128x(K) NT-GEMM mainloop (m97 structure) -------------------
// A [M,K] bf16 row-major, Bw [N,K] bf16 row-major (i.e. B^T input).
// acc[mi][ni]: C/D layout col = lane&15, row = (lane>>4)*4 + reg  [m89]
__device__ __forceinline__ void gemm_tile(
    const unsigned short* __restrict__ A,
    const unsigned short* __restrict__ Bw,
    int m0, int n0, int K,
    unsigned short* As, unsigned short* Bs,
    f32x4 acc[4][4])
{
  const int tid  = threadIdx.x;
  const int lane = tid & 63;
  const int w    = tid >> 6;
  const int wr   = w >> 1, wc = w & 1;
  const int lrow = lane & 15, lseg = (lane >> 4) * 8;

  const f32x4 fzero = {0.f, 0.f, 0.f, 0.f};
  #pragma unroll
  for (int i = 0; i < 4; ++i)
    #pragma unroll
    for (int j = 0; j < 4; ++j)
      acc[i][j] = fzero;

  for (int k0 = 0; k0 < K; k0 += BK) {
    #pragma unroll
    for (int c = 0; c < 2; ++c) {
      int i = tid + c * 256;           // 512 x 16B chunks per tile
      int row = i >> 2, cc = i & 3;    // 4 chunks per 32-elem row
      GLL(A  + (size_t)(m0 + row) * K + k0 + cc * 8, As + i * 8);
      GLL(Bw + (size_t)(n0 + row) * K + k0 + cc * 8, Bs + i * 8);
    }
    __syncthreads();
    bf16x8 af[4], bfr[4];
    #pragma unroll
    for (int mi = 0; mi < 4; ++mi)
      af[mi] = *(const bf16x8*)(As + (wr * 64 + mi * 16 + lrow) * BK + lseg);
    #pragma unroll
    for (int ni = 0; ni < 4; ++ni)
      bfr[ni] = *(const bf16x8*)(Bs + (wc * 64 + ni * 16 + lrow) * BK + lseg);
    #pragma unroll
    for (int mi = 0; mi < 4; ++mi)
      #pragma unroll
      for (int ni = 0; ni < 4; ++ni)
        acc[mi][ni] = __builtin_amdgcn_mfma_f32_16x16x32_bf16(af[mi], bfr[ni], acc[mi][ni], 0, 0, 0);
    __syncthreads();
  }
}

// ---- QKV projection + RoPE + head-split store ------------------------------
__global__ __launch_bounds__(256) void gemm_qkv(
    const unsigned short* __restrict__ Xb,
    const unsigned short* __restrict__ Wqb,
    const unsigned short* __restrict__ Wkb,
    const unsigned short* __restrict__ Wvb,
    const int* __restrict__ tpos,
    unsigned short* __restrict__ Qh,    // [B,H,S,64]
    unsigned short* __restrict__ Kh,    // [B,H,S,64]
    unsigned short* __restrict__ Vt)    // [B,H,64,S]
{
  __shared__ unsigned short As[BM * BK], Bs[BN * BK];
  const int z = blockIdx.z;
  const unsigned short* W = (z == 0) ? Wqb : (z == 1) ? Wkb : Wvb;
  const int m0 = blockIdx.x * BM, n0 = blockIdx.y * BN;
  f32x4 acc[4][4];
  gemm_tile(Xb, W, m0, n0, DMODEL, As, Bs, acc);

  const int lane = threadIdx.x & 63;
  const int w    = threadIdx.x >> 6;
  const int wr   = w >> 1, wc = w & 1;
  const int cb   = lane & 15, rb = (lane >> 4) * 4;
  unsigned short* dst = (z == 0) ? Qh : (z == 1) ? Kh : Vt;
  const float l2t = 13.28771237954945f / 32.0f;   // log2(10000)/32

  #pragma unroll
  for (int mi = 0; mi < 4; ++mi) {
    #pragma unroll
    for (int r = 0; r < 4; ++r) {
      const int m = m0 + wr * 64 + mi * 16 + rb + r;
      const int b = m >> 11, s = m & (SS - 1);
      const int pos = tpos[m];
      #pragma unroll
      for (int ni = 0; ni < 4; ++ni) {
        const int n = n0 + wc * 64 + ni * 16 + cb;
        const int h = n >> 6, d = n & 63;
        float v = acc[mi][ni][r];
        if (z < 2) {
          // RoPE pair (2j, 2j+1) lives in adjacent C-columns = lane^1
          float other = __shfl_xor(v, 1);
          int j = d >> 1;
          float ang = (float)pos * exp2f(-(float)j * l2t);
          float sn, cs;
          sincosf(ang, &sn, &cs);
          float res = (d & 1) ? (other * sn + v * cs) : (v * cs - other * sn);
          dst[((size_t)(b * NH + h) * SS + s) * DKH + d] = f2bf(res);
        } else {
          dst[((size_t)(b * NH + h) * DKH + d) * SS + s] = f2bf(v);
        }
      }
    }
  }
}

// ---- flash attention (causal), 4 waves x 16 q-rows, KV tiles of 64 ---------
__global__ __launch_bounds__(256) void attn(
    const unsigned short* __restrict__ Qh,
    const unsigned short* __restrict__ Kh,
    const unsigned short* __restrict__ Vt,
    unsigned short* __restrict__ comb)  // [B,S,1024]
{
  __shared__ unsigned short Ks[64 * 64];   // [kv][d]
  __shared__ unsigned short Vs[64 * 64];   // [d][kv]  (from transposed V)
  __shared__ unsigned short Ps[4 * 16 * 64]; // per-wave P [q][kv]
  const int bh = blockIdx.y;
  const int q0 = blockIdx.x * 64;
  const int tid = threadIdx.x, lane = tid & 63, w = tid >> 6;
  const int lc = lane & 15, lh = lane >> 4;

  // hoist Q fragments (A-operand: row = lane&15, kseg = (lane>>4)*8)
  const unsigned short* Qbase = Qh + ((size_t)bh * SS + q0 + w * 16 + lc) * DKH;
  bf16x8 qf0 = *(const bf16x8*)(Qbase + lh * 8);
  bf16x8 qf1 = *(const bf16x8*)(Qbase + lh * 8 + 32);

  const f32x4 fzero = {0.f, 0.f, 0.f, 0.f};
  f32x4 oacc[4];
  #pragma unroll
  for (int i = 0; i < 4; ++i) oacc[i] = fzero;
  float mrow[4] = {-3e38f, -3e38f, -3e38f, -3e38f};
  float lsum[4] = {0.f, 0.f, 0.f, 0.f};

  const unsigned short* kb = Kh + (size_t)bh * SS * DKH;
  const unsigned short* vb = Vt + (size_t)bh * DKH * SS;

  const int ntiles = blockIdx.x + 1;
  for (int t = 0; t < ntiles; ++t) {
    const int kv0 = t * 64;
    #pragma unroll
    for (int c = 0; c < 2; ++c) {
      int i = tid + c * 256;
      GLL(kb + (size_t)kv0 * DKH + i * 8, Ks + i * 8);        // contiguous 8KB
      int dr = i >> 3, cc = i & 7;
      GLL(vb + (size_t)dr * SS + kv0 + cc * 8, Vs + i * 8);   // [d][kv] rows
    }
    __syncthreads();

    // S = Q K^T  (B-operand: col kv = lane&15, dseg = (lane>>4)*8)
    f32x4 sacc[4];
    #pragma unroll
    for (int nf = 0; nf < 4; ++nf) sacc[nf] = fzero;
    #pragma unroll
    for (int nf = 0; nf < 4; ++nf) {
      bf16x8 kf0 = *(const bf16x8*)(Ks + (nf * 16 + lc) * 64 + lh * 8);
      bf16x8 kf1 = *(const bf16x8*)(Ks + (nf * 16 + lc) * 64 + lh * 8 + 32);
      sacc[nf] = __builtin_amdgcn_mfma_f32_16x16x32_bf16(qf0, kf0, sacc[nf], 0, 0, 0);
      sacc[nf] = __builtin_amdgcn_mfma_f32_16x16x32_bf16(qf1, kf1, sacc[nf], 0, 0, 0);
    }

    const bool diag = (t == blockIdx.x);
    float pv[4][4];
    float tmax[4] = {-3e38f, -3e38f, -3e38f, -3e38f};
    #pragma unroll
    for (int nf = 0; nf < 4; ++nf)
      #pragma unroll
      for (int r = 0; r < 4; ++r) {
        float sv = sacc[nf][r] * 0.125f;
        if (diag) {
          int kv = kv0 + nf * 16 + lc;
          int q  = q0 + w * 16 + lh * 4 + r;
          if (kv > q) sv = -3e38f;
        }
        pv[nf][r] = sv;
        tmax[r] = fmaxf(tmax[r], sv);
      }

    float alpha[4];
    #pragma unroll
    for (int r = 0; r < 4; ++r) {
      float tm = tmax[r];
      tm = fmaxf(tm, __shfl_xor(tm, 1));
      tm = fmaxf(tm, __shfl_xor(tm, 2));
      tm = fmaxf(tm, __shfl_xor(tm, 4));
      tm = fmaxf(tm, __shfl_xor(tm, 8));
      float mn = fmaxf(mrow[r], tm);
      alpha[r] = __expf(mrow[r] - mn);
      mrow[r] = mn;
    }
    float rsum[4] = {0.f, 0.f, 0.f, 0.f};
    #pragma unroll
    for (int nf = 0; nf < 4; ++nf)
      #pragma unroll
      for (int r = 0; r < 4; ++r) {
        float p = __expf(pv[nf][r] - mrow[r]);
        pv[nf][r] = p;
        rsum[r] += p;
      }
    #pragma unroll
    for (int r = 0; r < 4; ++r) {
      float rs = rsum[r];
      rs += __shfl_xor(rs, 1);
      rs += __shfl_xor(rs, 2);
      rs += __shfl_xor(rs, 4);
      rs += __shfl_xor(rs, 8);
      lsum[r] = lsum[r] * alpha[r] + rs;
      oacc[0][r] *= alpha[r];
      oacc[1][r] *= alpha[r];
      oacc[2][r] *= alpha[r];
      oacc[3][r] *= alpha[r];
    }

    // P (bf16) -> per-wave LDS to re-layout for PV A-operand
    #pragma unroll
    for (int nf = 0; nf < 4; ++nf)
      #pragma unroll
      for (int r = 0; r < 4; ++r)
        Ps[w * 1024 + (lh * 4 + r) * 64 + nf * 16 + lc] = f2bf(pv[nf][r]);
    __syncthreads();

    // O += P V   (A: P[q][kv], B: V[kv][d] read from Vs[d][kv])
    #pragma unroll
    for (int c = 0; c < 2; ++c) {
      bf16x8 pf = *(const bf16x8*)(Ps + w * 1024 + lc * 64 + lh * 8 + c * 32);
      #pragma unroll
      for (int df = 0; df < 4; ++df) {
        bf16x8 vf = *(const bf16x8*)(Vs + (df * 16 + lc) * 64 + lh * 8 + c * 32);
        oacc[df] = __builtin_amdgcn_mfma_f32_16x16x32_bf16(pf, vf, oacc[df], 0, 0, 0);
      }
    }
    __syncthreads();
  }

  const int b = bh >> 4, h = bh & 15;
  #pragma unroll
  for (int df = 0; df < 4; ++df)
    #pragma unroll
    for (int r = 0; r < 4; ++r) {
      int q = q0 + w * 16 + lh * 4 + r;
      int d = h * 64 + df * 16 + lc;
      comb[(size_t)(b * SS + q) * DMODEL + d] = f2bf(oacc[df][r] / lsum[r]);
    }
}

// ---- output projection -----------------------------------------------------
__global__ __launch_bounds__(256) void gemm_out(
    const unsigned short* __restrict__ Cb,
    const unsigned short* __restrict__ Wob,
    float* __restrict__ out)
{
  __shared__ unsigned short As[BM * BK], Bs[BN * BK];
  const int m0 = blockIdx.x * BM, n0 = blockIdx.y * BN;
  f32x4 acc[4][4];
  gemm_tile(Cb, Wob, m0, n0, DMODEL, As, Bs, acc);
  const int lane = threadIdx.x & 63;
  const int w    = threadIdx.x >> 6;
  const int wr   = w >> 1, wc = w & 1;
  const int cb   = lane & 15, rb = (lane >> 4) * 4;
  #pragma unroll
  for (int mi = 0; mi < 4; ++mi)
    #pragma unroll
    for (int ni = 0; ni < 4; ++ni)
      #pragma unroll
      for (int r = 0; r < 4; ++r) {
        int m = m0 + wr * 64 + mi * 16 + rb + r;
        int n = n0 + wc * 64 + ni * 16 + cb;
        out[(size_t)m * DMODEL + n] = acc[mi][ni][r];
      }
}

extern "C" void kernel_launch(void* const* d_in, const int* in_sizes, int n_in,
                              void* d_out, int out_size, void* d_ws, size_t ws_size,
                              hipStream_t stream) {
  (void)in_sizes; (void)n_in; (void)out_size; (void)ws_size;
  const float* X    = (const float*)d_in[0];
  const int*   tpos = (const int*)d_in[1];
  const float* Wq   = (const float*)d_in[2];
  const float* Wk   = (const float*)d_in[3];
  const float* Wv   = (const float*)d_in[4];
  const float* Wo   = (const float*)d_in[5];
  float* out = (float*)d_out;

  uint8_t* ws = (uint8_t*)d_ws;
  const size_t SZ_X = (size_t)MTOT * DMODEL * 2;    // 8 MB
  const size_t SZ_W = (size_t)DMODEL * DMODEL * 2;  // 2 MB
  const size_t SZ_H = (size_t)BB * NH * SS * DKH * 2; // 8 MB
  unsigned short* Xb   = (unsigned short*)(ws);
  unsigned short* Wqb  = (unsigned short*)(ws + SZ_X);
  unsigned short* Wkb  = (unsigned short*)(ws + SZ_X + SZ_W);
  unsigned short* Wvb  = (unsigned short*)(ws + SZ_X + 2 * SZ_W);
  unsigned short* Wob  = (unsigned short*)(ws + SZ_X + 3 * SZ_W);
  unsigned short* Qh   = (unsigned short*)(ws + SZ_X + 4 * SZ_W);
  unsigned short* Kh   = (unsigned short*)(ws + SZ_X + 4 * SZ_W + SZ_H);
  unsigned short* Vt   = (unsigned short*)(ws + SZ_X + 4 * SZ_W + 2 * SZ_H);
  unsigned short* comb = Xb;  // Xb dead after QKV projection

  cvt_bf16<<<dim3(MTOT * DMODEL / 8 / 256), dim3(256), 0, stream>>>(X, Xb, MTOT * DMODEL / 8);
  cvt_bf16<<<dim3(DMODEL * DMODEL / 8 / 256), dim3(256), 0, stream>>>(Wq, Wqb, DMODEL * DMODEL / 8);
  cvt_bf16<<<dim3(DMODEL * DMODEL / 8 / 256), dim3(256), 0, stream>>>(Wk, Wkb, DMODEL * DMODEL / 8);
  cvt_bf16<<<dim3(DMODEL * DMODEL / 8 / 256), dim3(256), 0, stream>>>(Wv, Wvb, DMODEL * DMODEL / 8);
  cvt_bf16<<<dim3(DMODEL * DMODEL / 8 / 256), dim3(256), 0, stream>>>(Wo, Wob, DMODEL * DMODEL / 8);

  gemm_qkv<<<dim3(MTOT / BM, DMODEL / BN, 3), dim3(256), 0, stream>>>(Xb, Wqb, Wkb, Wvb, tpos, Qh, Kh, Vt);
  attn<<<dim3(SS / 64, BB * NH), dim3(256), 0, stream>>>(Qh, Kh, Vt, comb);
  gemm_out<<<dim3(MTOT / BM, DMODEL / BN), dim3(256), 0, stream>>>(comb, Wob, out);
}

// Round 2
// 227.419 us; speedup vs baseline: 1.8539x; 1.8539x over previous
//
#include <hip/hip_runtime.h>
#include <hip/hip_bf16.h>
#include <stdint.h>

#define DMODEL 1024
#define NH 16
#define DKH 64
#define BB 2
#define SS 2048
#define MTOT (BB*SS)   // 4096

#define BM 128
#define BN 128
#define BK 32
#define TP 136   // padded LDS tile stride (elems): 272B rows, 16B-aligned

using f32x4  = __attribute__((ext_vector_type(4))) float;
using bf16x8 = __attribute__((ext_vector_type(8))) __bf16;

// async global->LDS, 16B per lane. LDS dest must be wave-uniform base + lane*16.
#define GLL(g, l) __builtin_amdgcn_global_load_lds( \
    (const __attribute__((address_space(1))) unsigned int*)(g), \
    (__attribute__((address_space(3))) unsigned int*)(l), 16, 0, 0)

__device__ __forceinline__ unsigned short f2bf(float f) {
  union { float f; uint32_t u; } v; v.f = f;
  uint32_t r = v.u + 0x7FFFu + ((v.u >> 16) & 1u);
  return (unsigned short)(r >> 16);
}

__global__ __launch_bounds__(256) void cvt_bf16(const float* __restrict__ src,
                                                unsigned short* __restrict__ dst, int n8) {
  int i = blockIdx.x * blockDim.x + threadIdx.x;
  if (i >= n8) return;
  const float4* s4 = (const float4*)src;
  float4 a = s4[2*i], b = s4[2*i+1];
  uint4 o;
  o.x = (uint32_t)f2bf(a.x) | ((uint32_t)f2bf(a.y) << 16);
  o.y = (uint32_t)f2bf(a.z) | ((uint32_t)f2bf(a.w) << 16);
  o.z = (uint32_t)f2bf(b.x) | ((uint32_t)f2bf(b.y) << 16);
  o.w = (uint32_t)f2bf(b.z) | ((uint32_t)f2bf(b.w) << 16);
  *(uint4*)(dst + (size_t)i * 8) = o;
}

// ---- shared 128x128x(K) NT-GEMM mainloop (m97 structure) -------------------
// A [M,K] bf16 row-major, Bw [N,K] bf16 row-major (i.e. B^T input).
// acc[mi][ni]: C/D layout col = lane&15, row = (lane>>4)*4 + reg  [m89]
__device__ __forceinline__ void gemm_tile(
    const unsigned short* __restrict__ A,
    const unsigned short* __restrict__ Bw,
    int m0, int n0, int K,
    unsigned short* As, unsigned short* Bs,
    f32x4 acc[4][4])
{
  const int tid  = threadIdx.x;
  const int lane = tid & 63;
  const int w    = tid >> 6;
  const int wr   = w >> 1, wc = w & 1;
  const int lrow = lane & 15, lseg = (lane >> 4) * 8;

  const f32x4 fzero = {0.f, 0.f, 0.f, 0.f};
  #pragma unroll
  for (int i = 0; i < 4; ++i)
    #pragma unroll
    for (int j = 0; j < 4; ++j)
      acc[i][j] = fzero;

  for (int k0 = 0; k0 < K; k0 += BK) {
    #pragma unroll
    for (int c = 0; c < 2; ++c) {
      int i = tid + c * 256;           // 512 x 16B chunks per tile
      int row = i >> 2, cc = i & 3;    // 4 chunks per 32-elem row
      GLL(A  + (size_t)(m0 + row) * K + k0 + cc * 8, As + i * 8);
      GLL(Bw + (size_t)(n0 + row) * K + k0 + cc * 8, Bs + i * 8);
    }
    __syncthreads();
    bf16x8 af[4], bfr[4];
    #pragma unroll
    for (int mi = 0; mi < 4; ++mi)
      af[mi] = *(const bf16x8*)(As + (wr * 64 + mi * 16 + lrow) * BK + lseg);
    #pragma unroll
    for (int ni = 0; ni < 4; ++ni)
      bfr[ni] = *(const bf16x8*)(Bs + (wc * 64 + ni * 16 + lrow) * BK + lseg);
    #pragma unroll
    for (int mi = 0; mi < 4; ++mi)
      #pragma unroll
      for (int ni = 0; ni < 4; ++ni)
        acc[mi][ni] = __builtin_amdgcn_mfma_f32_16x16x32_bf16(af[mi], bfr[ni], acc[mi][ni], 0, 0, 0);
    __syncthreads();
  }
}

// ---- QKV projection + RoPE + head-split store (LDS-staged epilogue) --------
__global__ __launch_bounds__(256) void gemm_qkv(
    const unsigned short* __restrict__ Xb,
    const unsigned short* __restrict__ Wqb,
    const unsigned short* __restrict__ Wkb,
    const unsigned short* __restrict__ Wvb,
    const int* __restrict__ tpos,
    unsigned short* __restrict__ Qh,    // [B,H,S,64]
    unsigned short* __restrict__ Kh,    // [B,H,S,64]
    unsigned short* __restrict__ Vt)    // [B,H,64,S]
{
  __shared__ unsigned short sm[BM * TP];   // 34 KB; first 16 KB doubles as As/Bs
  unsigned short* As = sm;
  unsigned short* Bs = sm + BM * BK;

  const int z = blockIdx.z;
  const unsigned short* W = (z == 0) ? Wqb : (z == 1) ? Wkb : Wvb;
  const int m0 = blockIdx.x * BM, n0 = blockIdx.y * BN;
  f32x4 acc[4][4];
  gemm_tile(Xb, W, m0, n0, DMODEL, As, Bs, acc);
  // mainloop ends with __syncthreads -> safe to reuse sm

  const int tid  = threadIdx.x;
  const int lane = tid & 63;
  const int w    = tid >> 6;
  const int wr   = w >> 1, wc = w & 1;
  const int cb   = lane & 15, rb = (lane >> 4) * 4;

  if (z < 2) {
    // tile [m_l][n_l]
    #pragma unroll
    for (int mi = 0; mi < 4; ++mi)
      #pragma unroll
      for (int ni = 0; ni < 4; ++ni)
        #pragma unroll
        for (int r = 0; r < 4; ++r)
          sm[(wr * 64 + mi * 16 + rb + r) * TP + wc * 64 + ni * 16 + cb] = f2bf(acc[mi][ni][r]);
  } else {
    // transposed tile [n_l][m_l]
    #pragma unroll
    for (int mi = 0; mi < 4; ++mi)
      #pragma unroll
      for (int ni = 0; ni < 4; ++ni)
        #pragma unroll
        for (int r = 0; r < 4; ++r)
          sm[(wc * 64 + ni * 16 + cb) * TP + wr * 64 + mi * 16 + rb + r] = f2bf(acc[mi][ni][r]);
  }
  __syncthreads();

  const int b = m0 >> 11;                 // whole block same batch (2048 % 128 == 0)
  const float l2t = 13.28771237954945f / 32.0f;   // log2(10000)/32

  if (z < 2) {
    unsigned short* dst = (z == 0) ? Qh : Kh;
    #pragma unroll
    for (int p = 0; p < 8; ++p) {
      const int m_l = p * 16 + (tid >> 4);
      const int ck  = tid & 15;
      bf16x8 vals = *(const bf16x8*)(sm + m_l * TP + ck * 8);
      const int m = m0 + m_l, s = m & (SS - 1);
      const int pos = tpos[m];
      const int n = n0 + ck * 8, h = n >> 6, dh = n & 63;
      union { unsigned short u[8]; uint4 v; } ov;
      #pragma unroll
      for (int e = 0; e < 4; ++e) {
        float x1 = (float)vals[2 * e], x2 = (float)vals[2 * e + 1];
        int j = (dh >> 1) + e;
        float ang = (float)pos * exp2f(-(float)j * l2t);
        float sn, cs;
        sincosf(ang, &sn, &cs);
        ov.u[2 * e]     = f2bf(x1 * cs - x2 * sn);
        ov.u[2 * e + 1] = f2bf(x1 * sn + x2 * cs);
      }
      *(uint4*)(dst + ((size_t)(b * NH + h) * SS + s) * DKH + dh) = ov.v;
    }
  } else {
    #pragma unroll
    for (int p = 0; p < 8; ++p) {
      const int n_l = p * 16 + (tid >> 4);
      const int ck  = tid & 15;
      bf16x8 vals = *(const bf16x8*)(sm + n_l * TP + ck * 8);
      const int n = n0 + n_l, h = n >> 6, dh = n & 63;
      const int m = m0 + ck * 8, s = m & (SS - 1);
      *(bf16x8*)(Vt + ((size_t)(b * NH + h) * DKH + dh) * SS + s) = vals;
    }
  }
}

// ---- flash attention (causal), 4 waves x 16 q-rows, KV tiles of 64 ---------
// LDS rows are 128B (64 bf16) = 8 x 16B chunks; all tiles use chunk ^= (row&7)
// XOR-swizzle, with the inverse permutation applied to the GLL *source*.
__global__ __launch_bounds__(256) void attn(
    const unsigned short* __restrict__ Qh,
    const unsigned short* __restrict__ Kh,
    const unsigned short* __restrict__ Vt,
    unsigned short* __restrict__ comb)  // [B,S,1024]
{
  __shared__ unsigned short Ks[64 * 64];   // [kv][d], swizzled
  __shared__ unsigned short Vs[64 * 64];   // [d][kv], swizzled
  __shared__ unsigned short Ps[4 * 16 * 64]; // per-wave P [q][kv], swizzled
  const int bh = blockIdx.y;
  const int q0 = blockIdx.x * 64;
  const int tid = threadIdx.x, lane = tid & 63, w = tid >> 6;
  const int lc = lane & 15, lh = lane >> 4;

  // hoist Q fragments (A-operand: row = lane&15, kseg = (lane>>4)*8)
  const unsigned short* Qbase = Qh + ((size_t)bh * SS + q0 + w * 16 + lc) * DKH;
  bf16x8 qf0 = *(const bf16x8*)(Qbase + lh * 8);
  bf16x8 qf1 = *(const bf16x8*)(Qbase + lh * 8 + 32);

  const f32x4 fzero = {0.f, 0.f, 0.f, 0.f};
  f32x4 oacc[4];
  #pragma unroll
  for (int i = 0; i < 4; ++i) oacc[i] = fzero;
  float mrow[4] = {-3e38f, -3e38f, -3e38f, -3e38f};
  float lsum[4] = {0.f, 0.f, 0.f, 0.f};

  const unsigned short* kb = Kh + (size_t)bh * SS * DKH;
  const unsigned short* vb = Vt + (size_t)bh * DKH * SS;

  const int ntiles = blockIdx.x + 1;
  for (int t = 0; t < ntiles; ++t) {
    const int kv0 = t * 64;
    #pragma unroll
    for (int c = 0; c < 2; ++c) {
      int i = tid + c * 256;             // 512 x 16B chunks
      int row = i >> 3, pc = i & 7;
      int sc = pc ^ (row & 7);           // inverse swizzle on global source
      GLL(kb + (size_t)(kv0 + row) * DKH + sc * 8, Ks + i * 8);
      GLL(vb + (size_t)row * SS + kv0 + sc * 8, Vs + i * 8);
    }
    __syncthreads();

    // S = Q K^T  (B-operand: col kv = lane&15, dseg = (lane>>4)*8)
    f32x4 sacc[4];
    #pragma unroll
    for (int nf = 0; nf < 4; ++nf) sacc[nf] = fzero;
    #pragma unroll
    for (int nf = 0; nf < 4; ++nf) {
      int row = nf * 16 + lc;
      bf16x8 kf0 = *(const bf16x8*)(Ks + row * 64 + (lh ^ (row & 7)) * 8);
      bf16x8 kf1 = *(const bf16x8*)(Ks + row * 64 + ((lh + 4) ^ (row & 7)) * 8);
      sacc[nf] = __builtin_amdgcn_mfma_f32_16x16x32_bf16(qf0, kf0, sacc[nf], 0, 0, 0);
      sacc[nf] = __builtin_amdgcn_mfma_f32_16x16x32_bf16(qf1, kf1, sacc[nf], 0, 0, 0);
    }

    const bool diag = (t == blockIdx.x);
    float pv[4][4];
    float tmax[4] = {-3e38f, -3e38f, -3e38f, -3e38f};
    #pragma unroll
    for (int nf = 0; nf < 4; ++nf)
      #pragma unroll
      for (int r = 0; r < 4; ++r) {
        float sv = sacc[nf][r] * 0.125f;
        if (diag) {
          int kv = kv0 + nf * 16 + lc;
          int q  = q0 + w * 16 + lh * 4 + r;
          if (kv > q) sv = -3e38f;
        }
        pv[nf][r] = sv;
        tmax[r] = fmaxf(tmax[r], sv);
      }

    float alpha[4];
    #pragma unroll
    for (int r = 0; r < 4; ++r) {
      float tm = tmax[r];
      tm = fmaxf(tm, __shfl_xor(tm, 1));
      tm = fmaxf(tm, __shfl_xor(tm, 2));
      tm = fmaxf(tm, __shfl_xor(tm, 4));
      tm = fmaxf(tm, __shfl_xor(tm, 8));
      float mn = fmaxf(mrow[r], tm);
      alpha[r] = __expf(mrow[r] - mn);
      mrow[r] = mn;
    }
    float rsum[4] = {0.f, 0.f, 0.f, 0.f};
    #pragma unroll
    for (int nf = 0; nf < 4; ++nf)
      #pragma unroll
      for (int r = 0; r < 4; ++r) {
        float p = __expf(pv[nf][r] - mrow[r]);
        pv[nf][r] = p;
        rsum[r] += p;
      }
    #pragma unroll
    for (int r = 0; r < 4; ++r) {
      float rs = rsum[r];
      rs += __shfl_xor(rs, 1);
      rs += __shfl_xor(rs, 2);
      rs += __shfl_xor(rs, 4);
      rs += __shfl_xor(rs, 8);
      lsum[r] = lsum[r] * alpha[r] + rs;
      oacc[0][r] *= alpha[r];
      oacc[1][r] *= alpha[r];
      oacc[2][r] *= alpha[r];
      oacc[3][r] *= alpha[r];
    }

    // P (bf16) -> per-wave LDS (swizzled) to re-layout for PV A-operand
    #pragma unroll
    for (int nf = 0; nf < 4; ++nf)
      #pragma unroll
      for (int r = 0; r < 4; ++r) {
        int prow = lh * 4 + r;
        int pcol = nf * 16 + lc;
        int pch  = (pcol >> 3) ^ (prow & 7);
        Ps[w * 1024 + prow * 64 + pch * 8 + (pcol & 7)] = f2bf(pv[nf][r]);
      }
    __syncthreads();

    // O += P V   (A: P[q][kv], B: V[kv][d] read from Vs[d][kv])
    #pragma unroll
    for (int c = 0; c < 2; ++c) {
      bf16x8 pf = *(const bf16x8*)(Ps + w * 1024 + lc * 64 + ((c * 4 + lh) ^ (lc & 7)) * 8);
      #pragma unroll
      for (int df = 0; df < 4; ++df) {
        int row = df * 16 + lc;
        bf16x8 vf = *(const bf16x8*)(Vs + row * 64 + ((c * 4 + lh) ^ (row & 7)) * 8);
        oacc[df] = __builtin_amdgcn_mfma_f32_16x16x32_bf16(pf, vf, oacc[df], 0, 0, 0);
      }
    }
    __syncthreads();
  }

  const int b = bh >> 4, h = bh & 15;
  #pragma unroll
  for (int df = 0; df < 4; ++df)
    #pragma unroll
    for (int r = 0; r < 4; ++r) {
      int q = q0 + w * 16 + lh * 4 + r;
      int d = h * 64 + df * 16 + lc;
      comb[(size_t)(b * SS + q) * DMODEL + d] = f2bf(oacc[df][r] / lsum[r]);
    }
}

// ---- output projection -----------------------------------------------------
__global__ __launch_bounds__(256) void gemm_out(
    const unsigned short* __restrict__ Cb,
    const unsigned short* __restrict__ Wob,
    float* __restrict__ out)
{
  __shared__ unsigned short As[BM * BK], Bs[BN * BK];
  const int m0 = blockIdx.x * BM, n0 = blockIdx.y * BN;
  f32x4 acc[4][4];
  gemm_tile(Cb, Wob, m0, n0, DMODEL, As, Bs, acc);
  const int lane = threadIdx.x & 63;
  const int w    = threadIdx.x >> 6;
  const int wr   = w >> 1, wc = w & 1;
  const int cb   = lane & 15, rb = (lane >> 4) * 4;
  #pragma unroll
  for (int mi = 0; mi < 4; ++mi)
    #pragma unroll
    for (int ni = 0; ni < 4; ++ni)
      #pragma unroll
      for (int r = 0; r < 4; ++r) {
        int m = m0 + wr * 64 + mi * 16 + rb + r;
        int n = n0 + wc * 64 + ni * 16 + cb;
        out[(size_t)m * DMODEL + n] = acc[mi][ni][r];
      }
}

extern "C" void kernel_launch(void* const* d_in, const int* in_sizes, int n_in,
                              void* d_out, int out_size, void* d_ws, size_t ws_size,
                              hipStream_t stream) {
  (void)in_sizes; (void)n_in; (void)out_size; (void)ws_size;
  const float* X    = (const float*)d_in[0];
  const int*   tpos = (const int*)d_in[1];
  const float* Wq   = (const float*)d_in[2];
  const float* Wk   = (const float*)d_in[3];
  const float* Wv   = (const float*)d_in[4];
  const float* Wo   = (const float*)d_in[5];
  float* out = (float*)d_out;

  uint8_t* ws = (uint8_t*)d_ws;
  const size_t SZ_X = (size_t)MTOT * DMODEL * 2;    // 8 MB
  const size_t SZ_W = (size_t)DMODEL * DMODEL * 2;  // 2 MB
  const size_t SZ_H = (size_t)BB * NH * SS * DKH * 2; // 8 MB
  unsigned short* Xb   = (unsigned short*)(ws);
  unsigned short* Wqb  = (unsigned short*)(ws + SZ_X);
  unsigned short* Wkb  = (unsigned short*)(ws + SZ_X + SZ_W);
  unsigned short* Wvb  = (unsigned short*)(ws + SZ_X + 2 * SZ_W);
  unsigned short* Wob  = (unsigned short*)(ws + SZ_X + 3 * SZ_W);
  unsigned short* Qh   = (unsigned short*)(ws + SZ_X + 4 * SZ_W);
  unsigned short* Kh   = (unsigned short*)(ws + SZ_X + 4 * SZ_W + SZ_H);
  unsigned short* Vt   = (unsigned short*)(ws + SZ_X + 4 * SZ_W + 2 * SZ_H);
  unsigned short* comb = Xb;  // Xb dead after QKV projection

  cvt_bf16<<<dim3(MTOT * DMODEL / 8 / 256), dim3(256), 0, stream>>>(X, Xb, MTOT * DMODEL / 8);
  cvt_bf16<<<dim3(DMODEL * DMODEL / 8 / 256), dim3(256), 0, stream>>>(Wq, Wqb, DMODEL * DMODEL / 8);
  cvt_bf16<<<dim3(DMODEL * DMODEL / 8 / 256), dim3(256), 0, stream>>>(Wk, Wkb, DMODEL * DMODEL / 8);
  cvt_bf16<<<dim3(DMODEL * DMODEL / 8 / 256), dim3(256), 0, stream>>>(Wv, Wvb, DMODEL * DMODEL / 8);
  cvt_bf16<<<dim3(DMODEL * DMODEL / 8 / 256), dim3(256), 0, stream>>>(Wo, Wob, DMODEL * DMODEL / 8);

  gemm_qkv<<<dim3(MTOT / BM, DMODEL / BN, 3), dim3(256), 0, stream>>>(Xb, Wqb, Wkb, Wvb, tpos, Qh, Kh, Vt);
  attn<<<dim3(SS / 64, BB * NH), dim3(256), 0, stream>>>(Qh, Kh, Vt, comb);
  gemm_out<<<dim3(MTOT / BM, DMODEL / BN), dim3(256), 0, stream>>>(comb, Wob, out);
}

// Round 4
// 144.833 us; speedup vs baseline: 2.9110x; 1.5702x over previous
//
#include <hip/hip_runtime.h>
#include <hip/hip_bf16.h>
#include <stdint.h>

#define DMODEL 1024
#define NH 16
#define DKH 64
#define BB 2
#define SS 2048
#define MTOT (BB*SS)   // 4096

#define BM 128
#define BN 128
#define BK 32
#define TP 136   // padded LDS tile stride (elems): 272B rows, 16B-aligned

using f32x4  = __attribute__((ext_vector_type(4))) float;
using bf16x8 = __attribute__((ext_vector_type(8))) __bf16;

// async global->LDS, 16B per lane. LDS dest must be wave-uniform base + lane*16.
#define GLL(g, l) __builtin_amdgcn_global_load_lds( \
    (const __attribute__((address_space(1))) unsigned int*)(g), \
    (__attribute__((address_space(3))) unsigned int*)(l), 16, 0, 0)

__device__ __forceinline__ unsigned short f2bf(float f) {
  union { float f; uint32_t u; } v; v.f = f;
  uint32_t r = v.u + 0x7FFFu + ((v.u >> 16) & 1u);
  return (unsigned short)(r >> 16);
}

__global__ __launch_bounds__(256) void cvt_bf16(const float* __restrict__ src,
                                                unsigned short* __restrict__ dst, int n8) {
  int i = blockIdx.x * blockDim.x + threadIdx.x;
  if (i >= n8) return;
  const float4* s4 = (const float4*)src;
  float4 a = s4[2*i], b = s4[2*i+1];
  uint4 o;
  o.x = (uint32_t)f2bf(a.x) | ((uint32_t)f2bf(a.y) << 16);
  o.y = (uint32_t)f2bf(a.z) | ((uint32_t)f2bf(a.w) << 16);
  o.z = (uint32_t)f2bf(b.x) | ((uint32_t)f2bf(b.y) << 16);
  o.w = (uint32_t)f2bf(b.z) | ((uint32_t)f2bf(b.w) << 16);
  *(uint4*)(dst + (size_t)i * 8) = o;
}

// ---- shared 128x128x(K) NT-GEMM mainloop (m97 structure) -------------------
__device__ __forceinline__ void gemm_tile(
    const unsigned short* __restrict__ A,
    const unsigned short* __restrict__ Bw,
    int m0, int n0, int K,
    unsigned short* As, unsigned short* Bs,
    f32x4 acc[4][4])
{
  const int tid  = threadIdx.x;
  const int lane = tid & 63;
  const int w    = tid >> 6;
  const int wr   = w >> 1, wc = w & 1;
  const int lrow = lane & 15, lseg = (lane >> 4) * 8;

  const f32x4 fzero = {0.f, 0.f, 0.f, 0.f};
  #pragma unroll
  for (int i = 0; i < 4; ++i)
    #pragma unroll
    for (int j = 0; j < 4; ++j)
      acc[i][j] = fzero;

  for (int k0 = 0; k0 < K; k0 += BK) {
    #pragma unroll
    for (int c = 0; c < 2; ++c) {
      int i = tid + c * 256;           // 512 x 16B chunks per tile
      int row = i >> 2, cc = i & 3;    // 4 chunks per 32-elem row
      GLL(A  + (size_t)(m0 + row) * K + k0 + cc * 8, As + i * 8);
      GLL(Bw + (size_t)(n0 + row) * K + k0 + cc * 8, Bs + i * 8);
    }
    __syncthreads();
    bf16x8 af[4], bfr[4];
    #pragma unroll
    for (int mi = 0; mi < 4; ++mi)
      af[mi] = *(const bf16x8*)(As + (wr * 64 + mi * 16 + lrow) * BK + lseg);
    #pragma unroll
    for (int ni = 0; ni < 4; ++ni)
      bfr[ni] = *(const bf16x8*)(Bs + (wc * 64 + ni * 16 + lrow) * BK + lseg);
    #pragma unroll
    for (int mi = 0; mi < 4; ++mi)
      #pragma unroll
      for (int ni = 0; ni < 4; ++ni)
        acc[mi][ni] = __builtin_amdgcn_mfma_f32_16x16x32_bf16(af[mi], bfr[ni], acc[mi][ni], 0, 0, 0);
    __syncthreads();
  }
}

// ---- QKV projection + RoPE + head-split store (LDS-staged epilogue) --------
__global__ __launch_bounds__(256) void gemm_qkv(
    const unsigned short* __restrict__ Xb,
    const unsigned short* __restrict__ Wqb,
    const unsigned short* __restrict__ Wkb,
    const unsigned short* __restrict__ Wvb,
    const int* __restrict__ tpos,
    unsigned short* __restrict__ Qh,    // [B,H,S,64]
    unsigned short* __restrict__ Kh,    // [B,H,S,64]
    unsigned short* __restrict__ Vt)    // [B,H,64,S]
{
  __shared__ unsigned short sm[BM * TP];   // 34 KB; first 16 KB doubles as As/Bs
  unsigned short* As = sm;
  unsigned short* Bs = sm + BM * BK;

  const int z = blockIdx.z;
  const unsigned short* W = (z == 0) ? Wqb : (z == 1) ? Wkb : Wvb;
  const int m0 = blockIdx.x * BM, n0 = blockIdx.y * BN;
  f32x4 acc[4][4];
  gemm_tile(Xb, W, m0, n0, DMODEL, As, Bs, acc);
  // mainloop ends with __syncthreads -> safe to reuse sm

  const int tid  = threadIdx.x;
  const int lane = tid & 63;
  const int w    = tid >> 6;
  const int wr   = w >> 1, wc = w & 1;
  const int cb   = lane & 15, rb = (lane >> 4) * 4;

  if (z < 2) {
    #pragma unroll
    for (int mi = 0; mi < 4; ++mi)
      #pragma unroll
      for (int ni = 0; ni < 4; ++ni)
        #pragma unroll
        for (int r = 0; r < 4; ++r)
          sm[(wr * 64 + mi * 16 + rb + r) * TP + wc * 64 + ni * 16 + cb] = f2bf(acc[mi][ni][r]);
  } else {
    #pragma unroll
    for (int mi = 0; mi < 4; ++mi)
      #pragma unroll
      for (int ni = 0; ni < 4; ++ni)
        #pragma unroll
        for (int r = 0; r < 4; ++r)
          sm[(wc * 64 + ni * 16 + cb) * TP + wr * 64 + mi * 16 + rb + r] = f2bf(acc[mi][ni][r]);
  }
  __syncthreads();

  const int b = m0 >> 11;
  const float l2t = 13.28771237954945f / 32.0f;   // log2(10000)/32

  if (z < 2) {
    unsigned short* dst = (z == 0) ? Qh : Kh;
    #pragma unroll
    for (int p = 0; p < 8; ++p) {
      const int m_l = p * 16 + (tid >> 4);
      const int ck  = tid & 15;
      bf16x8 vals = *(const bf16x8*)(sm + m_l * TP + ck * 8);
      const int m = m0 + m_l, s = m & (SS - 1);
      const int pos = tpos[m];
      const int n = n0 + ck * 8, h = n >> 6, dh = n & 63;
      union { unsigned short u[8]; uint4 v; } ov;
      #pragma unroll
      for (int e = 0; e < 4; ++e) {
        float x1 = (float)vals[2 * e], x2 = (float)vals[2 * e + 1];
        int j = (dh >> 1) + e;
        float ang = (float)pos * exp2f(-(float)j * l2t);
        float sn, cs;
        sincosf(ang, &sn, &cs);
        ov.u[2 * e]     = f2bf(x1 * cs - x2 * sn);
        ov.u[2 * e + 1] = f2bf(x1 * sn + x2 * cs);
      }
      *(uint4*)(dst + ((size_t)(b * NH + h) * SS + s) * DKH + dh) = ov.v;
    }
  } else {
    #pragma unroll
    for (int p = 0; p < 8; ++p) {
      const int n_l = p * 16 + (tid >> 4);
      const int ck  = tid & 15;
      bf16x8 vals = *(const bf16x8*)(sm + n_l * TP + ck * 8);
      const int n = n0 + n_l, h = n >> 6, dh = n & 63;
      const int m = m0 + ck * 8, s = m & (SS - 1);
      *(bf16x8*)(Vt + ((size_t)(b * NH + h) * DKH + dh) * SS + s) = vals;
    }
  }
}

// ---- flash attention (causal) ----------------------------------------------
// Balanced: block x handles q-tiles x and 31-x (33 KV-iterations each).
// Double-buffered K/V LDS, 1 raw barrier + 1 vmcnt(0) per tile; STAGE(t+1)
// issued mid-compute(t). Swapped QK^T (mfma(K,Q)): lane owns q = lc and 16 of
// the 64 kv scores; row stats need a 4-lane group reduce over xor{16,32}.
__global__ __launch_bounds__(256) void attn(
    const unsigned short* __restrict__ Qh,
    const unsigned short* __restrict__ Kh,
    const unsigned short* __restrict__ Vt,
    unsigned short* __restrict__ comb)  // [B,S,1024]
{
  __shared__ unsigned short Ks[2][64 * 64];   // [kv][d], chunk^row swizzled
  __shared__ unsigned short Vs[2][64 * 64];   // [d][kv], chunk^row swizzled
  __shared__ unsigned short Ps[4 * 16 * 64];  // per-wave P [q][kv], swizzled
  const int bh  = blockIdx.y;
  const int tid = threadIdx.x, lane = tid & 63, w = tid >> 6;
  const int lc = lane & 15, lh = lane >> 4;

  const unsigned short* kb = Kh + (size_t)bh * SS * DKH;
  const unsigned short* vb = Vt + (size_t)bh * DKH * SS;
  const int b = bh >> 4, h = bh & 15;
  const f32x4 fzero = {0.f, 0.f, 0.f, 0.f};
  const float SC = 0.18033688011112042f;   // 0.125 * log2(e)

  auto STAGE = [&](int t, int buf) {
    const int kv0 = t * 64;
    #pragma unroll
    for (int c = 0; c < 2; ++c) {
      int i = tid + c * 256;             // 512 x 16B chunks
      int row = i >> 3, pc = i & 7;
      int sc = pc ^ (row & 7);           // inverse swizzle on global source
      GLL(kb + (size_t)(kv0 + row) * DKH + sc * 8, &Ks[buf][i * 8]);
      GLL(vb + (size_t)row * SS + kv0 + sc * 8, &Vs[buf][i * 8]);
    }
  };

  auto RUN = [&](int qt, int p0) {
    const int q0 = qt * 64;
    const int qlane = q0 + w * 16 + lc;  // this lane's q-row (stats owner)
    const unsigned short* Qb = Qh + ((size_t)bh * SS + q0 + w * 16 + lc) * DKH;
    bf16x8 qf0 = *(const bf16x8*)(Qb + lh * 8);        // d 0..31 slice
    bf16x8 qf1 = *(const bf16x8*)(Qb + lh * 8 + 32);   // d 32..63 slice

    f32x4 oacc[4];
    #pragma unroll
    for (int i = 0; i < 4; ++i) oacc[i] = fzero;
    float mrow = -1e30f, lsum = 0.f;

    const int nt = qt + 1;
    STAGE(0, p0);
    for (int t = 0; t < nt; ++t) {
      const int cur = (p0 + t) & 1;
      asm volatile("s_waitcnt vmcnt(0)" ::: "memory");  // STAGE(t) landed
      __builtin_amdgcn_s_barrier();                     // all waves' stage done

      // S^T = K Q^T : A = K rows (kv), B = Q^T cols (q)
      f32x4 sacc[4];
      #pragma unroll
      for (int nf = 0; nf < 4; ++nf) {
        const int row = nf * 16 + lc;
        bf16x8 kf0 = *(const bf16x8*)(&Ks[cur][row * 64 + ((lh) ^ (row & 7)) * 8]);
        bf16x8 kf1 = *(const bf16x8*)(&Ks[cur][row * 64 + ((lh + 4) ^ (row & 7)) * 8]);
        sacc[nf] = __builtin_amdgcn_mfma_f32_16x16x32_bf16(kf0, qf0, fzero, 0, 0, 0);
        sacc[nf] = __builtin_amdgcn_mfma_f32_16x16x32_bf16(kf1, qf1, sacc[nf], 0, 0, 0);
      }

      if (t + 1 < nt) STAGE(t + 1, cur ^ 1);   // prefetch hides under softmax+PV

      // softmax: lane holds 16 of 64 kv for q = lc; group = lanes xor{16,32}
      const bool diag = (t == qt);
      const int kv0 = t * 64;
      float sv[4][4];
      float tm = -1e30f;
      #pragma unroll
      for (int nf = 0; nf < 4; ++nf)
        #pragma unroll
        for (int r = 0; r < 4; ++r) {
          float x = sacc[nf][r] * SC;
          if (diag) {
            int kv = kv0 + nf * 16 + lh * 4 + r;
            if (kv > qlane) x = -1e30f;
          }
          sv[nf][r] = x;
          tm = fmaxf(tm, x);
        }
      // group max over the 4 lanes holding this q-row
      tm = fmaxf(tm, __shfl_xor(tm, 16));
      tm = fmaxf(tm, __shfl_xor(tm, 32));
      float mn = fmaxf(mrow, tm);
      float alpha = exp2f(mrow - mn);   // uniform across the 4-lane group
      mrow = mn;
      float rs = 0.f;
      #pragma unroll
      for (int nf = 0; nf < 4; ++nf)
        #pragma unroll
        for (int r = 0; r < 4; ++r) {
          float p = exp2f(sv[nf][r] - mn);
          sv[nf][r] = p;
          rs += p;
        }
      lsum = lsum * alpha + rs;   // per-lane partial; group-summed at epilogue

      // rescale O: need alpha of q = lh*4+r -> broadcast from lane lh*4+r
      #pragma unroll
      for (int r = 0; r < 4; ++r) {
        float ar = __shfl(alpha, lh * 4 + r);
        #pragma unroll
        for (int df = 0; df < 4; ++df) oacc[df][r] *= ar;
      }

      // P -> per-wave LDS (swizzled, b64-packed); no barrier (same wave)
      #pragma unroll
      for (int nf = 0; nf < 4; ++nf) {
        uint32_t u0 = (uint32_t)f2bf(sv[nf][0]) | ((uint32_t)f2bf(sv[nf][1]) << 16);
        uint32_t u1 = (uint32_t)f2bf(sv[nf][2]) | ((uint32_t)f2bf(sv[nf][3]) << 16);
        int chunk = nf * 2 + (lh >> 1);
        int sw = chunk ^ (lc & 7);
        uint32_t* p = (uint32_t*)&Ps[w * 1024 + lc * 64 + sw * 8 + (lh & 1) * 4];
        p[0] = u0; p[1] = u1;
      }

      // O += P V : A = P [q][kv], B = V [kv][d] (from Vs[d][kv])
      #pragma unroll
      for (int c = 0; c < 2; ++c) {
        bf16x8 pf = *(const bf16x8*)(&Ps[w * 1024 + lc * 64 + ((c * 4 + lh) ^ (lc & 7)) * 8]);
        #pragma unroll
        for (int df = 0; df < 4; ++df) {
          const int row = df * 16 + lc;
          bf16x8 vf = *(const bf16x8*)(&Vs[cur][row * 64 + ((c * 4 + lh) ^ (row & 7)) * 8]);
          oacc[df] = __builtin_amdgcn_mfma_f32_16x16x32_bf16(pf, vf, oacc[df], 0, 0, 0);
        }
      }
    }

    // group-sum lsum (alpha history identical across the 4 lanes per q-row)
    lsum += __shfl_xor(lsum, 16);
    lsum += __shfl_xor(lsum, 32);

    // epilogue: O row = q (lh*4+r), col = d (df*16+lc); lsum held by lane q
    #pragma unroll
    for (int r = 0; r < 4; ++r) {
      float ls = __shfl(lsum, lh * 4 + r);
      float inv = 1.f / ls;
      const int q = q0 + w * 16 + lh * 4 + r;
      #pragma unroll
      for (int df = 0; df < 4; ++df) {
        const int d = h * 64 + df * 16 + lc;
        comb[((size_t)(b * SS + q)) * DMODEL + d] = f2bf(oacc[df][r] * inv);
      }
    }
  };

  const int qtA = blockIdx.x;          // 0..15
  const int qtB = 31 - qtA;            // 31..16  -> total 33 tiles per block
  RUN(qtA, 0);
  RUN(qtB, (qtA + 1) & 1);
}

// ---- output projection -----------------------------------------------------
__global__ __launch_bounds__(256) void gemm_out(
    const unsigned short* __restrict__ Cb,
    const unsigned short* __restrict__ Wob,
    float* __restrict__ out)
{
  __shared__ unsigned short As[BM * BK], Bs[BN * BK];
  const int m0 = blockIdx.x * BM, n0 = blockIdx.y * BN;
  f32x4 acc[4][4];
  gemm_tile(Cb, Wob, m0, n0, DMODEL, As, Bs, acc);
  const int lane = threadIdx.x & 63;
  const int w    = threadIdx.x >> 6;
  const int wr   = w >> 1, wc = w & 1;
  const int cb   = lane & 15, rb = (lane >> 4) * 4;
  #pragma unroll
  for (int mi = 0; mi < 4; ++mi)
    #pragma unroll
    for (int ni = 0; ni < 4; ++ni)
      #pragma unroll
      for (int r = 0; r < 4; ++r) {
        int m = m0 + wr * 64 + mi * 16 + rb + r;
        int n = n0 + wc * 64 + ni * 16 + cb;
        out[(size_t)m * DMODEL + n] = acc[mi][ni][r];
      }
}

extern "C" void kernel_launch(void* const* d_in, const int* in_sizes, int n_in,
                              void* d_out, int out_size, void* d_ws, size_t ws_size,
                              hipStream_t stream) {
  (void)in_sizes; (void)n_in; (void)out_size; (void)ws_size;
  const float* X    = (const float*)d_in[0];
  const int*   tpos = (const int*)d_in[1];
  const float* Wq   = (const float*)d_in[2];
  const float* Wk   = (const float*)d_in[3];
  const float* Wv   = (const float*)d_in[4];
  const float* Wo   = (const float*)d_in[5];
  float* out = (float*)d_out;

  uint8_t* ws = (uint8_t*)d_ws;
  const size_t SZ_X = (size_t)MTOT * DMODEL * 2;      // 8 MB
  const size_t SZ_W = (size_t)DMODEL * DMODEL * 2;    // 2 MB
  const size_t SZ_H = (size_t)BB * NH * SS * DKH * 2; // 8 MB
  unsigned short* Xb   = (unsigned short*)(ws);
  unsigned short* Wqb  = (unsigned short*)(ws + SZ_X);
  unsigned short* Wkb  = (unsigned short*)(ws + SZ_X + SZ_W);
  unsigned short* Wvb  = (unsigned short*)(ws + SZ_X + 2 * SZ_W);
  unsigned short* Wob  = (unsigned short*)(ws + SZ_X + 3 * SZ_W);
  unsigned short* Qh   = (unsigned short*)(ws + SZ_X + 4 * SZ_W);
  unsigned short* Kh   = (unsigned short*)(ws + SZ_X + 4 * SZ_W + SZ_H);
  unsigned short* Vt   = (unsigned short*)(ws + SZ_X + 4 * SZ_W + 2 * SZ_H);
  unsigned short* comb = Xb;  // Xb dead after QKV projection

  cvt_bf16<<<dim3(MTOT * DMODEL / 8 / 256), dim3(256), 0, stream>>>(X, Xb, MTOT * DMODEL / 8);
  cvt_bf16<<<dim3(DMODEL * DMODEL / 8 / 256), dim3(256), 0, stream>>>(Wq, Wqb, DMODEL * DMODEL / 8);
  cvt_bf16<<<dim3(DMODEL * DMODEL / 8 / 256), dim3(256), 0, stream>>>(Wk, Wkb, DMODEL * DMODEL / 8);
  cvt_bf16<<<dim3(DMODEL * DMODEL / 8 / 256), dim3(256), 0, stream>>>(Wv, Wvb, DMODEL * DMODEL / 8);
  cvt_bf16<<<dim3(DMODEL * DMODEL / 8 / 256), dim3(256), 0, stream>>>(Wo, Wob, DMODEL * DMODEL / 8);

  gemm_qkv<<<dim3(MTOT / BM, DMODEL / BN, 3), dim3(256), 0, stream>>>(Xb, Wqb, Wkb, Wvb, tpos, Qh, Kh, Vt);
  attn<<<dim3(16, BB * NH), dim3(256), 0, stream>>>(Qh, Kh, Vt, comb);
  gemm_out<<<dim3(MTOT / BM, DMODEL / BN), dim3(256), 0, stream>>>(comb, Wob, out);
}

// Round 5
// 140.312 us; speedup vs baseline: 3.0049x; 1.0322x over previous
//
#include <hip/hip_runtime.h>
#include <hip/hip_bf16.h>
#include <stdint.h>

#define DMODEL 1024
#define NH 16
#define DKH 64
#define BB 2
#define SS 2048
#define MTOT (BB*SS)   // 4096

#define BM 128
#define BN 128
#define BK 32
#define TP 136   // padded LDS tile stride (elems): 272B rows, 16B-aligned

using f32x4  = __attribute__((ext_vector_type(4))) float;
using bf16x8 = __attribute__((ext_vector_type(8))) __bf16;

// async global->LDS, 16B per lane. LDS dest must be wave-uniform base + lane*16.
#define GLL(g, l) __builtin_amdgcn_global_load_lds( \
    (const __attribute__((address_space(1))) unsigned int*)(g), \
    (__attribute__((address_space(3))) unsigned int*)(l), 16, 0, 0)

__device__ __forceinline__ unsigned short f2bf(float f) {
  union { float f; uint32_t u; } v; v.f = f;
  uint32_t r = v.u + 0x7FFFu + ((v.u >> 16) & 1u);
  return (unsigned short)(r >> 16);
}

__global__ __launch_bounds__(256) void cvt_bf16(const float* __restrict__ src,
                                                unsigned short* __restrict__ dst, int n8) {
  int i = blockIdx.x * blockDim.x + threadIdx.x;
  if (i >= n8) return;
  const float4* s4 = (const float4*)src;
  float4 a = s4[2*i], b = s4[2*i+1];
  uint4 o;
  o.x = (uint32_t)f2bf(a.x) | ((uint32_t)f2bf(a.y) << 16);
  o.y = (uint32_t)f2bf(a.z) | ((uint32_t)f2bf(a.w) << 16);
  o.z = (uint32_t)f2bf(b.x) | ((uint32_t)f2bf(b.y) << 16);
  o.w = (uint32_t)f2bf(b.z) | ((uint32_t)f2bf(b.w) << 16);
  *(uint4*)(dst + (size_t)i * 8) = o;
}

// all 4 weight matrices in one launch; dst segments are contiguous in ws
__global__ __launch_bounds__(256) void cvt_w4(const float* __restrict__ w0,
                                              const float* __restrict__ w1,
                                              const float* __restrict__ w2,
                                              const float* __restrict__ w3,
                                              unsigned short* __restrict__ dst) {
  const int zz = blockIdx.y;
  const float* src = (zz == 0) ? w0 : (zz == 1) ? w1 : (zz == 2) ? w2 : w3;
  int i = blockIdx.x * blockDim.x + threadIdx.x;   // 0 .. 131071
  const float4* s4 = (const float4*)src;
  float4 a = s4[2*i], b = s4[2*i+1];
  uint4 o;
  o.x = (uint32_t)f2bf(a.x) | ((uint32_t)f2bf(a.y) << 16);
  o.y = (uint32_t)f2bf(a.z) | ((uint32_t)f2bf(a.w) << 16);
  o.z = (uint32_t)f2bf(b.x) | ((uint32_t)f2bf(b.y) << 16);
  o.w = (uint32_t)f2bf(b.z) | ((uint32_t)f2bf(b.w) << 16);
  *(uint4*)(dst + (size_t)zz * DMODEL * DMODEL + (size_t)i * 8) = o;
}

// ---- shared 128x128x(K) NT-GEMM mainloop (m97 structure) -------------------
__device__ __forceinline__ void gemm_tile(
    const unsigned short* __restrict__ A,
    const unsigned short* __restrict__ Bw,
    int m0, int n0, int K,
    unsigned short* As, unsigned short* Bs,
    f32x4 acc[4][4])
{
  const int tid  = threadIdx.x;
  const int lane = tid & 63;
  const int w    = tid >> 6;
  const int wr   = w >> 1, wc = w & 1;
  const int lrow = lane & 15, lseg = (lane >> 4) * 8;

  const f32x4 fzero = {0.f, 0.f, 0.f, 0.f};
  #pragma unroll
  for (int i = 0; i < 4; ++i)
    #pragma unroll
    for (int j = 0; j < 4; ++j)
      acc[i][j] = fzero;

  for (int k0 = 0; k0 < K; k0 += BK) {
    #pragma unroll
    for (int c = 0; c < 2; ++c) {
      int i = tid + c * 256;           // 512 x 16B chunks per tile
      int row = i >> 2, cc = i & 3;    // 4 chunks per 32-elem row
      GLL(A  + (size_t)(m0 + row) * K + k0 + cc * 8, As + i * 8);
      GLL(Bw + (size_t)(n0 + row) * K + k0 + cc * 8, Bs + i * 8);
    }
    __syncthreads();
    bf16x8 af[4], bfr[4];
    #pragma unroll
    for (int mi = 0; mi < 4; ++mi)
      af[mi] = *(const bf16x8*)(As + (wr * 64 + mi * 16 + lrow) * BK + lseg);
    #pragma unroll
    for (int ni = 0; ni < 4; ++ni)
      bfr[ni] = *(const bf16x8*)(Bs + (wc * 64 + ni * 16 + lrow) * BK + lseg);
    #pragma unroll
    for (int mi = 0; mi < 4; ++mi)
      #pragma unroll
      for (int ni = 0; ni < 4; ++ni)
        acc[mi][ni] = __builtin_amdgcn_mfma_f32_16x16x32_bf16(af[mi], bfr[ni], acc[mi][ni], 0, 0, 0);
    __syncthreads();
  }
}

// ---- QKV projection + RoPE + head-split store (LDS-staged epilogue) --------
// Q is pre-scaled by 0.125*log2(e) so attention works directly in exp2 domain.
__global__ __launch_bounds__(256) void gemm_qkv(
    const unsigned short* __restrict__ Xb,
    const unsigned short* __restrict__ Wqb,
    const unsigned short* __restrict__ Wkb,
    const unsigned short* __restrict__ Wvb,
    const int* __restrict__ tpos,
    unsigned short* __restrict__ Qh,    // [B,H,S,64]
    unsigned short* __restrict__ Kh,    // [B,H,S,64]
    unsigned short* __restrict__ Vt)    // [B,H,64,S]
{
  __shared__ unsigned short sm[BM * TP];   // 34 KB; first 16 KB doubles as As/Bs
  unsigned short* As = sm;
  unsigned short* Bs = sm + BM * BK;

  const int z = blockIdx.z;
  const unsigned short* W = (z == 0) ? Wqb : (z == 1) ? Wkb : Wvb;
  const int m0 = blockIdx.x * BM, n0 = blockIdx.y * BN;
  f32x4 acc[4][4];
  gemm_tile(Xb, W, m0, n0, DMODEL, As, Bs, acc);
  // mainloop ends with __syncthreads -> safe to reuse sm

  const int tid  = threadIdx.x;
  const int lane = tid & 63;
  const int w    = tid >> 6;
  const int wr   = w >> 1, wc = w & 1;
  const int cb   = lane & 15, rb = (lane >> 4) * 4;

  if (z < 2) {
    #pragma unroll
    for (int mi = 0; mi < 4; ++mi)
      #pragma unroll
      for (int ni = 0; ni < 4; ++ni)
        #pragma unroll
        for (int r = 0; r < 4; ++r)
          sm[(wr * 64 + mi * 16 + rb + r) * TP + wc * 64 + ni * 16 + cb] = f2bf(acc[mi][ni][r]);
  } else {
    #pragma unroll
    for (int mi = 0; mi < 4; ++mi)
      #pragma unroll
      for (int ni = 0; ni < 4; ++ni)
        #pragma unroll
        for (int r = 0; r < 4; ++r)
          sm[(wc * 64 + ni * 16 + cb) * TP + wr * 64 + mi * 16 + rb + r] = f2bf(acc[mi][ni][r]);
  }
  __syncthreads();

  const int b = m0 >> 11;
  const float l2t = 13.28771237954945f / 32.0f;   // log2(10000)/32
  const float qsc = (z == 0) ? 0.18033688011112042f : 1.0f;  // 0.125*log2(e)

  if (z < 2) {
    unsigned short* dst = (z == 0) ? Qh : Kh;
    #pragma unroll
    for (int p = 0; p < 8; ++p) {
      const int m_l = p * 16 + (tid >> 4);
      const int ck  = tid & 15;
      bf16x8 vals = *(const bf16x8*)(sm + m_l * TP + ck * 8);
      const int m = m0 + m_l, s = m & (SS - 1);
      const int pos = tpos[m];
      const int n = n0 + ck * 8, h = n >> 6, dh = n & 63;
      union { unsigned short u[8]; uint4 v; } ov;
      #pragma unroll
      for (int e = 0; e < 4; ++e) {
        float x1 = (float)vals[2 * e], x2 = (float)vals[2 * e + 1];
        int j = (dh >> 1) + e;
        float ang = (float)pos * exp2f(-(float)j * l2t);
        float sn, cs;
        sincosf(ang, &sn, &cs);
        sn *= qsc; cs *= qsc;
        ov.u[2 * e]     = f2bf(x1 * cs - x2 * sn);
        ov.u[2 * e + 1] = f2bf(x1 * sn + x2 * cs);
      }
      *(uint4*)(dst + ((size_t)(b * NH + h) * SS + s) * DKH + dh) = ov.v;
    }
  } else {
    #pragma unroll
    for (int p = 0; p < 8; ++p) {
      const int n_l = p * 16 + (tid >> 4);
      const int ck  = tid & 15;
      bf16x8 vals = *(const bf16x8*)(sm + n_l * TP + ck * 8);
      const int n = n0 + n_l, h = n >> 6, dh = n & 63;
      const int m = m0 + ck * 8, s = m & (SS - 1);
      *(bf16x8*)(Vt + ((size_t)(b * NH + h) * DKH + dh) * SS + s) = vals;
    }
  }
}

// ---- flash attention (causal), fused dual-chain --------------------------
// Block x handles q-tiles A=x and B=31-x in ONE kv loop (t=0..31-x); chain A
// is active while t<=x. Both chains share the staged K/V tile and the K/V
// fragment reads. 1 barrier + 1 vmcnt(0) per iteration; STAGE(t+1) issued
// mid-compute. Swapped QK^T (mfma(K,Q)): lane owns q=lc; kv axis split over
// lanes xor{16,32} -> 2-shuffle group max; lsum group-summed at epilogue.
__global__ __launch_bounds__(256) void attn(
    const unsigned short* __restrict__ Qh,
    const unsigned short* __restrict__ Kh,
    const unsigned short* __restrict__ Vt,
    unsigned short* __restrict__ comb)  // [B,S,1024]
{
  __shared__ unsigned short Ks[2][64 * 64];    // [kv][d], chunk^row swizzled
  __shared__ unsigned short Vs[2][64 * 64];    // [d][kv], chunk^row swizzled
  __shared__ unsigned short Ps[2][4][16 * 64]; // per-chain per-wave P, swizzled
  const int bh  = blockIdx.y;
  const int tid = threadIdx.x, lane = tid & 63, w = tid >> 6;
  const int lc = lane & 15, lh = lane >> 4;

  const unsigned short* kb = Kh + (size_t)bh * SS * DKH;
  const unsigned short* vb = Vt + (size_t)bh * DKH * SS;
  const int b = bh >> 4, h = bh & 15;
  const f32x4 fzero = {0.f, 0.f, 0.f, 0.f};

  const int qtA = blockIdx.x;       // 0..15
  const int qtB = 31 - qtA;         // 31..16
  const int ntB = qtB + 1;

  auto STAGE = [&](int t, int buf) {
    const int kv0 = t * 64;
    #pragma unroll
    for (int c = 0; c < 2; ++c) {
      int i = tid + c * 256;             // 512 x 16B chunks
      int row = i >> 3, pc = i & 7;
      int sc = pc ^ (row & 7);           // inverse swizzle on global source
      GLL(kb + (size_t)(kv0 + row) * DKH + sc * 8, &Ks[buf][i * 8]);
      GLL(vb + (size_t)row * SS + kv0 + sc * 8, &Vs[buf][i * 8]);
    }
  };

  const unsigned short* QbA = Qh + ((size_t)bh * SS + qtA * 64 + w * 16 + lc) * DKH;
  const unsigned short* QbB = Qh + ((size_t)bh * SS + qtB * 64 + w * 16 + lc) * DKH;
  bf16x8 qA0 = *(const bf16x8*)(QbA + lh * 8);
  bf16x8 qA1 = *(const bf16x8*)(QbA + lh * 8 + 32);
  bf16x8 qB0 = *(const bf16x8*)(QbB + lh * 8);
  bf16x8 qB1 = *(const bf16x8*)(QbB + lh * 8 + 32);

  f32x4 oA[4], oB[4];
  #pragma unroll
  for (int i = 0; i < 4; ++i) { oA[i] = fzero; oB[i] = fzero; }
  float mA = -1e30f, mB = -1e30f, lA = 0.f, lB = 0.f;

  // softmax (exp2 domain; scale pre-folded into Q) + P pack into per-wave LDS
  auto SM = [&](f32x4 (&sacc)[4], int qt, int t, float& mrow, float& lsum,
                f32x4 (&oacc)[4], unsigned short* psw) {
    const bool diag = (t == qt);
    const int kv0 = t * 64;
    const int qlane = qt * 64 + w * 16 + lc;
    float sv[4][4];
    float tm = -1e30f;
    #pragma unroll
    for (int nf = 0; nf < 4; ++nf)
      #pragma unroll
      for (int r = 0; r < 4; ++r) {
        float x = sacc[nf][r];
        if (diag && (kv0 + nf * 16 + lh * 4 + r) > qlane) x = -1e30f;
        sv[nf][r] = x;
        tm = fmaxf(tm, x);
      }
    tm = fmaxf(tm, __shfl_xor(tm, 16));
    tm = fmaxf(tm, __shfl_xor(tm, 32));
    // defer-max: skip rescale while max growth <= 8 (P bounded by 2^8)
    if (!__all(tm <= mrow + 8.f)) {
      float mn = fmaxf(mrow, tm);
      float alpha = exp2f(mrow - mn);
      mrow = mn;
      lsum *= alpha;
      #pragma unroll
      for (int r = 0; r < 4; ++r) {
        float ar = __shfl(alpha, lh * 4 + r);
        #pragma unroll
        for (int df = 0; df < 4; ++df) oacc[df][r] *= ar;
      }
    }
    float rs = 0.f;
    #pragma unroll
    for (int nf = 0; nf < 4; ++nf)
      #pragma unroll
      for (int r = 0; r < 4; ++r) {
        float p = exp2f(sv[nf][r] - mrow);
        sv[nf][r] = p;
        rs += p;
      }
    lsum += rs;
    #pragma unroll
    for (int nf = 0; nf < 4; ++nf) {
      uint32_t u0, u1;
      asm("v_cvt_pk_bf16_f32 %0, %1, %2" : "=v"(u0) : "v"(sv[nf][0]), "v"(sv[nf][1]));
      asm("v_cvt_pk_bf16_f32 %0, %1, %2" : "=v"(u1) : "v"(sv[nf][2]), "v"(sv[nf][3]));
      int swz = (nf * 2 + (lh >> 1)) ^ (lc & 7);
      uint32_t* p = (uint32_t*)&psw[lc * 64 + swz * 8 + (lh & 1) * 4];
      p[0] = u0; p[1] = u1;
    }
  };

  STAGE(0, 0);
  for (int t = 0; t < ntB; ++t) {
    const int cur = t & 1;
    const bool actA = (t <= qtA);
    asm volatile("s_waitcnt vmcnt(0)" ::: "memory");  // this wave's STAGE(t) landed
    __builtin_amdgcn_s_barrier();                     // all waves' stage done

    // QK^T for both chains; K fragments shared
    f32x4 sB[4], sA[4];
    __builtin_amdgcn_s_setprio(1);
    if (actA) {
      #pragma unroll
      for (int nf = 0; nf < 4; ++nf) {
        const int row = nf * 16 + lc;
        bf16x8 kf0 = *(const bf16x8*)(&Ks[cur][row * 64 + ((lh) ^ (row & 7)) * 8]);
        bf16x8 kf1 = *(const bf16x8*)(&Ks[cur][row * 64 + ((lh + 4) ^ (row & 7)) * 8]);
        sB[nf] = __builtin_amdgcn_mfma_f32_16x16x32_bf16(kf0, qB0, fzero, 0, 0, 0);
        sB[nf] = __builtin_amdgcn_mfma_f32_16x16x32_bf16(kf1, qB1, sB[nf], 0, 0, 0);
        sA[nf] = __builtin_amdgcn_mfma_f32_16x16x32_bf16(kf0, qA0, fzero, 0, 0, 0);
        sA[nf] = __builtin_amdgcn_mfma_f32_16x16x32_bf16(kf1, qA1, sA[nf], 0, 0, 0);
      }
    } else {
      #pragma unroll
      for (int nf = 0; nf < 4; ++nf) {
        const int row = nf * 16 + lc;
        bf16x8 kf0 = *(const bf16x8*)(&Ks[cur][row * 64 + ((lh) ^ (row & 7)) * 8]);
        bf16x8 kf1 = *(const bf16x8*)(&Ks[cur][row * 64 + ((lh + 4) ^ (row & 7)) * 8]);
        sB[nf] = __builtin_amdgcn_mfma_f32_16x16x32_bf16(kf0, qB0, fzero, 0, 0, 0);
        sB[nf] = __builtin_amdgcn_mfma_f32_16x16x32_bf16(kf1, qB1, sB[nf], 0, 0, 0);
      }
    }
    __builtin_amdgcn_s_setprio(0);

    if (t + 1 < ntB) STAGE(t + 1, cur ^ 1);   // prefetch hides under softmax+PV

    SM(sB, qtB, t, mB, lB, oB, &Ps[0][w][0]);
    if (actA) SM(sA, qtA, t, mA, lA, oA, &Ps[1][w][0]);

    // O += P V ; V fragments shared between chains
    __builtin_amdgcn_s_setprio(1);
    if (actA) {
      #pragma unroll
      for (int c = 0; c < 2; ++c) {
        bf16x8 pB = *(const bf16x8*)(&Ps[0][w][lc * 64 + ((c * 4 + lh) ^ (lc & 7)) * 8]);
        bf16x8 pA = *(const bf16x8*)(&Ps[1][w][lc * 64 + ((c * 4 + lh) ^ (lc & 7)) * 8]);
        #pragma unroll
        for (int df = 0; df < 4; ++df) {
          const int row = df * 16 + lc;
          bf16x8 vf = *(const bf16x8*)(&Vs[cur][row * 64 + ((c * 4 + lh) ^ (row & 7)) * 8]);
          oB[df] = __builtin_amdgcn_mfma_f32_16x16x32_bf16(pB, vf, oB[df], 0, 0, 0);
          oA[df] = __builtin_amdgcn_mfma_f32_16x16x32_bf16(pA, vf, oA[df], 0, 0, 0);
        }
      }
    } else {
      #pragma unroll
      for (int c = 0; c < 2; ++c) {
        bf16x8 pB = *(const bf16x8*)(&Ps[0][w][lc * 64 + ((c * 4 + lh) ^ (lc & 7)) * 8]);
        #pragma unroll
        for (int df = 0; df < 4; ++df) {
          const int row = df * 16 + lc;
          bf16x8 vf = *(const bf16x8*)(&Vs[cur][row * 64 + ((c * 4 + lh) ^ (row & 7)) * 8]);
          oB[df] = __builtin_amdgcn_mfma_f32_16x16x32_bf16(pB, vf, oB[df], 0, 0, 0);
        }
      }
    }
    __builtin_amdgcn_s_setprio(0);
  }

  auto EPI = [&](int qt, float lsum, f32x4 (&oacc)[4]) {
    lsum += __shfl_xor(lsum, 16);
    lsum += __shfl_xor(lsum, 32);
    const int q0 = qt * 64;
    #pragma unroll
    for (int r = 0; r < 4; ++r) {
      float ls = __shfl(lsum, lh * 4 + r);
      float inv = 1.f / ls;
      const int q = q0 + w * 16 + lh * 4 + r;
      #pragma unroll
      for (int df = 0; df < 4; ++df) {
        const int d = h * 64 + df * 16 + lc;
        comb[((size_t)(b * SS + q)) * DMODEL + d] = f2bf(oacc[df][r] * inv);
      }
    }
  };
  EPI(qtB, lB, oB);
  EPI(qtA, lA, oA);
}

// ---- output projection -----------------------------------------------------
__global__ __launch_bounds__(256) void gemm_out(
    const unsigned short* __restrict__ Cb,
    const unsigned short* __restrict__ Wob,
    float* __restrict__ out)
{
  __shared__ unsigned short As[BM * BK], Bs[BN * BK];
  const int m0 = blockIdx.x * BM, n0 = blockIdx.y * BN;
  f32x4 acc[4][4];
  gemm_tile(Cb, Wob, m0, n0, DMODEL, As, Bs, acc);
  const int lane = threadIdx.x & 63;
  const int w    = threadIdx.x >> 6;
  const int wr   = w >> 1, wc = w & 1;
  const int cb   = lane & 15, rb = (lane >> 4) * 4;
  #pragma unroll
  for (int mi = 0; mi < 4; ++mi)
    #pragma unroll
    for (int ni = 0; ni < 4; ++ni)
      #pragma unroll
      for (int r = 0; r < 4; ++r) {
        int m = m0 + wr * 64 + mi * 16 + rb + r;
        int n = n0 + wc * 64 + ni * 16 + cb;
        out[(size_t)m * DMODEL + n] = acc[mi][ni][r];
      }
}

extern "C" void kernel_launch(void* const* d_in, const int* in_sizes, int n_in,
                              void* d_out, int out_size, void* d_ws, size_t ws_size,
                              hipStream_t stream) {
  (void)in_sizes; (void)n_in; (void)out_size; (void)ws_size;
  const float* X    = (const float*)d_in[0];
  const int*   tpos = (const int*)d_in[1];
  const float* Wq   = (const float*)d_in[2];
  const float* Wk   = (const float*)d_in[3];
  const float* Wv   = (const float*)d_in[4];
  const float* Wo   = (const float*)d_in[5];
  float* out = (float*)d_out;

  uint8_t* ws = (uint8_t*)d_ws;
  const size_t SZ_X = (size_t)MTOT * DMODEL * 2;      // 8 MB
  const size_t SZ_W = (size_t)DMODEL * DMODEL * 2;    // 2 MB
  const size_t SZ_H = (size_t)BB * NH * SS * DKH * 2; // 8 MB
  unsigned short* Xb   = (unsigned short*)(ws);
  unsigned short* Wqb  = (unsigned short*)(ws + SZ_X);
  unsigned short* Wkb  = (unsigned short*)(ws + SZ_X + SZ_W);
  unsigned short* Wvb  = (unsigned short*)(ws + SZ_X + 2 * SZ_W);
  unsigned short* Wob  = (unsigned short*)(ws + SZ_X + 3 * SZ_W);
  unsigned short* Qh   = (unsigned short*)(ws + SZ_X + 4 * SZ_W);
  unsigned short* Kh   = (unsigned short*)(ws + SZ_X + 4 * SZ_W + SZ_H);
  unsigned short* Vt   = (unsigned short*)(ws + SZ_X + 4 * SZ_W + 2 * SZ_H);
  unsigned short* comb = Xb;  // Xb dead after QKV projection

  cvt_bf16<<<dim3(MTOT * DMODEL / 8 / 256), dim3(256), 0, stream>>>(X, Xb, MTOT * DMODEL / 8);
  cvt_w4<<<dim3(DMODEL * DMODEL / 8 / 256, 4), dim3(256), 0, stream>>>(Wq, Wk, Wv, Wo, Wqb);

  gemm_qkv<<<dim3(MTOT / BM, DMODEL / BN, 3), dim3(256), 0, stream>>>(Xb, Wqb, Wkb, Wvb, tpos, Qh, Kh, Vt);
  attn<<<dim3(16, BB * NH), dim3(256), 0, stream>>>(Qh, Kh, Vt, comb);
  gemm_out<<<dim3(MTOT / BM, DMODEL / BN), dim3(256), 0, stream>>>(comb, Wob, out);
}

// Round 6
// 132.188 us; speedup vs baseline: 3.1895x; 1.0615x over previous
//
#include <hip/hip_runtime.h>
#include <hip/hip_bf16.h>
#include <stdint.h>

#define DMODEL 1024
#define NH 16
#define DKH 64
#define BB 2
#define SS 2048
#define MTOT (BB*SS)   // 4096

#define BM 128
#define BN 128
#define BK 32
#define TP 136   // padded LDS tile stride (elems): 272B rows, 16B-aligned

using f32x4  = __attribute__((ext_vector_type(4))) float;
using bf16x8 = __attribute__((ext_vector_type(8))) __bf16;

// async global->LDS, 16B per lane. LDS dest must be wave-uniform base + lane*16.
#define GLL(g, l) __builtin_amdgcn_global_load_lds( \
    (const __attribute__((address_space(1))) unsigned int*)(g), \
    (__attribute__((address_space(3))) unsigned int*)(l), 16, 0, 0)

__device__ __forceinline__ unsigned short f2bf(float f) {
  union { float f; uint32_t u; } v; v.f = f;
  uint32_t r = v.u + 0x7FFFu + ((v.u >> 16) & 1u);
  return (unsigned short)(r >> 16);
}

__global__ __launch_bounds__(256) void cvt_bf16(const float* __restrict__ src,
                                                unsigned short* __restrict__ dst, int n8) {
  int i = blockIdx.x * blockDim.x + threadIdx.x;
  if (i >= n8) return;
  const float4* s4 = (const float4*)src;
  float4 a = s4[2*i], b = s4[2*i+1];
  uint4 o;
  o.x = (uint32_t)f2bf(a.x) | ((uint32_t)f2bf(a.y) << 16);
  o.y = (uint32_t)f2bf(a.z) | ((uint32_t)f2bf(a.w) << 16);
  o.z = (uint32_t)f2bf(b.x) | ((uint32_t)f2bf(b.y) << 16);
  o.w = (uint32_t)f2bf(b.z) | ((uint32_t)f2bf(b.w) << 16);
  *(uint4*)(dst + (size_t)i * 8) = o;
}

// all 4 weight matrices in one launch; dst segments are contiguous in ws
__global__ __launch_bounds__(256) void cvt_w4(const float* __restrict__ w0,
                                              const float* __restrict__ w1,
                                              const float* __restrict__ w2,
                                              const float* __restrict__ w3,
                                              unsigned short* __restrict__ dst) {
  const int zz = blockIdx.y;
  const float* src = (zz == 0) ? w0 : (zz == 1) ? w1 : (zz == 2) ? w2 : w3;
  int i = blockIdx.x * blockDim.x + threadIdx.x;   // 0 .. 131071
  const float4* s4 = (const float4*)src;
  float4 a = s4[2*i], b = s4[2*i+1];
  uint4 o;
  o.x = (uint32_t)f2bf(a.x) | ((uint32_t)f2bf(a.y) << 16);
  o.y = (uint32_t)f2bf(a.z) | ((uint32_t)f2bf(a.w) << 16);
  o.z = (uint32_t)f2bf(b.x) | ((uint32_t)f2bf(b.y) << 16);
  o.w = (uint32_t)f2bf(b.z) | ((uint32_t)f2bf(b.w) << 16);
  *(uint4*)(dst + (size_t)zz * DMODEL * DMODEL + (size_t)i * 8) = o;
}

// ---- shared 128x128x(K) NT-GEMM mainloop (m97 structure) -------------------
__device__ __forceinline__ void gemm_tile(
    const unsigned short* __restrict__ A,
    const unsigned short* __restrict__ Bw,
    int m0, int n0, int K,
    unsigned short* As, unsigned short* Bs,
    f32x4 acc[4][4])
{
  const int tid  = threadIdx.x;
  const int lane = tid & 63;
  const int w    = tid >> 6;
  const int wr   = w >> 1, wc = w & 1;
  const int lrow = lane & 15, lseg = (lane >> 4) * 8;

  const f32x4 fzero = {0.f, 0.f, 0.f, 0.f};
  #pragma unroll
  for (int i = 0; i < 4; ++i)
    #pragma unroll
    for (int j = 0; j < 4; ++j)
      acc[i][j] = fzero;

  for (int k0 = 0; k0 < K; k0 += BK) {
    #pragma unroll
    for (int c = 0; c < 2; ++c) {
      int i = tid + c * 256;           // 512 x 16B chunks per tile
      int row = i >> 2, cc = i & 3;    // 4 chunks per 32-elem row
      GLL(A  + (size_t)(m0 + row) * K + k0 + cc * 8, As + i * 8);
      GLL(Bw + (size_t)(n0 + row) * K + k0 + cc * 8, Bs + i * 8);
    }
    __syncthreads();
    bf16x8 af[4], bfr[4];
    #pragma unroll
    for (int mi = 0; mi < 4; ++mi)
      af[mi] = *(const bf16x8*)(As + (wr * 64 + mi * 16 + lrow) * BK + lseg);
    #pragma unroll
    for (int ni = 0; ni < 4; ++ni)
      bfr[ni] = *(const bf16x8*)(Bs + (wc * 64 + ni * 16 + lrow) * BK + lseg);
    #pragma unroll
    for (int mi = 0; mi < 4; ++mi)
      #pragma unroll
      for (int ni = 0; ni < 4; ++ni)
        acc[mi][ni] = __builtin_amdgcn_mfma_f32_16x16x32_bf16(af[mi], bfr[ni], acc[mi][ni], 0, 0, 0);
    __syncthreads();
  }
}

// ---- QKV projection + RoPE + head-split store (LDS-staged epilogue) --------
// Q is pre-scaled by 0.125*log2(e) so attention works directly in exp2 domain.
__global__ __launch_bounds__(256) void gemm_qkv(
    const unsigned short* __restrict__ Xb,
    const unsigned short* __restrict__ Wqb,
    const unsigned short* __restrict__ Wkb,
    const unsigned short* __restrict__ Wvb,
    const int* __restrict__ tpos,
    unsigned short* __restrict__ Qh,    // [B,H,S,64]
    unsigned short* __restrict__ Kh,    // [B,H,S,64]
    unsigned short* __restrict__ Vt)    // [B,H,64,S]
{
  __shared__ unsigned short sm[BM * TP];   // 34 KB; first 16 KB doubles as As/Bs
  unsigned short* As = sm;
  unsigned short* Bs = sm + BM * BK;

  const int z = blockIdx.z;
  const unsigned short* W = (z == 0) ? Wqb : (z == 1) ? Wkb : Wvb;
  const int m0 = blockIdx.x * BM, n0 = blockIdx.y * BN;
  f32x4 acc[4][4];
  gemm_tile(Xb, W, m0, n0, DMODEL, As, Bs, acc);
  // mainloop ends with __syncthreads -> safe to reuse sm

  const int tid  = threadIdx.x;
  const int lane = tid & 63;
  const int w    = tid >> 6;
  const int wr   = w >> 1, wc = w & 1;
  const int cb   = lane & 15, rb = (lane >> 4) * 4;

  if (z < 2) {
    #pragma unroll
    for (int mi = 0; mi < 4; ++mi)
      #pragma unroll
      for (int ni = 0; ni < 4; ++ni)
        #pragma unroll
        for (int r = 0; r < 4; ++r)
          sm[(wr * 64 + mi * 16 + rb + r) * TP + wc * 64 + ni * 16 + cb] = f2bf(acc[mi][ni][r]);
  } else {
    #pragma unroll
    for (int mi = 0; mi < 4; ++mi)
      #pragma unroll
      for (int ni = 0; ni < 4; ++ni)
        #pragma unroll
        for (int r = 0; r < 4; ++r)
          sm[(wc * 64 + ni * 16 + cb) * TP + wr * 64 + mi * 16 + rb + r] = f2bf(acc[mi][ni][r]);
  }
  __syncthreads();

  const int b = m0 >> 11;
  const float l2t = 13.28771237954945f / 32.0f;   // log2(10000)/32
  const float qsc = (z == 0) ? 0.18033688011112042f : 1.0f;  // 0.125*log2(e)

  if (z < 2) {
    unsigned short* dst = (z == 0) ? Qh : Kh;
    #pragma unroll
    for (int p = 0; p < 8; ++p) {
      const int m_l = p * 16 + (tid >> 4);
      const int ck  = tid & 15;
      bf16x8 vals = *(const bf16x8*)(sm + m_l * TP + ck * 8);
      const int m = m0 + m_l, s = m & (SS - 1);
      const int pos = tpos[m];
      const int n = n0 + ck * 8, h = n >> 6, dh = n & 63;
      union { unsigned short u[8]; uint4 v; } ov;
      #pragma unroll
      for (int e = 0; e < 4; ++e) {
        float x1 = (float)vals[2 * e], x2 = (float)vals[2 * e + 1];
        int j = (dh >> 1) + e;
        float ang = (float)pos * exp2f(-(float)j * l2t);
        float sn, cs;
        sincosf(ang, &sn, &cs);
        sn *= qsc; cs *= qsc;
        ov.u[2 * e]     = f2bf(x1 * cs - x2 * sn);
        ov.u[2 * e + 1] = f2bf(x1 * sn + x2 * cs);
      }
      *(uint4*)(dst + ((size_t)(b * NH + h) * SS + s) * DKH + dh) = ov.v;
    }
  } else {
    #pragma unroll
    for (int p = 0; p < 8; ++p) {
      const int n_l = p * 16 + (tid >> 4);
      const int ck  = tid & 15;
      bf16x8 vals = *(const bf16x8*)(sm + n_l * TP + ck * 8);
      const int n = n0 + n_l, h = n >> 6, dh = n & 63;
      const int m = m0 + ck * 8, s = m & (SS - 1);
      *(bf16x8*)(Vt + ((size_t)(b * NH + h) * DKH + dh) * SS + s) = vals;
    }
  }
}

// ---- flash attention (causal), single-chain, occupancy-optimized -----------
// Grid 1024 = 32 qt x 32 bh, all co-resident (40KB LDS -> 4 blocks/CU,
// 16 waves/CU). idx->(qt,bh) mapping pairs {j,31-j} on each CU for balance.
// Diagonal tile peeled (mask-free main loop). Double-buffered K/V, 1 barrier
// + 1 vmcnt(0) per tile, STAGE(t+1) prefetch under softmax+PV. Swapped QK^T.
__global__ __launch_bounds__(256) void attn(
    const unsigned short* __restrict__ Qh,
    const unsigned short* __restrict__ Kh,
    const unsigned short* __restrict__ Vt,
    unsigned short* __restrict__ comb)  // [B,S,1024]
{
  __shared__ unsigned short Ks[2][64 * 64];  // [kv][d], chunk^row swizzled
  __shared__ unsigned short Vs[2][64 * 64];  // [d][kv], chunk^row swizzled
  __shared__ unsigned short Ps[4][16 * 64];  // per-wave P, swizzled

  const int idx = blockIdx.x;          // 0..1023
  const int u = idx & 255, v = idx >> 8;
  const int j = u >> 3;
  const int bh = (u & 7) + 8 * v;
  const int qt = (v & 1) ? j : 31 - j; // per-CU resident set {j,31-j,j,31-j}

  const int tid = threadIdx.x, lane = tid & 63, w = tid >> 6;
  const int lc = lane & 15, lh = lane >> 4;

  const unsigned short* kb = Kh + (size_t)bh * SS * DKH;
  const unsigned short* vb = Vt + (size_t)bh * DKH * SS;
  const int b = bh >> 4, h = bh & 15;
  const f32x4 fzero = {0.f, 0.f, 0.f, 0.f};

  auto STAGE = [&](int t, int buf) {
    const int kv0 = t * 64;
    #pragma unroll
    for (int c = 0; c < 2; ++c) {
      int i = tid + c * 256;             // 512 x 16B chunks
      int row = i >> 3, pc = i & 7;
      int sc = pc ^ (row & 7);           // inverse swizzle on global source
      GLL(kb + (size_t)(kv0 + row) * DKH + sc * 8, &Ks[buf][i * 8]);
      GLL(vb + (size_t)row * SS + kv0 + sc * 8, &Vs[buf][i * 8]);
    }
  };

  const unsigned short* Qb = Qh + ((size_t)bh * SS + qt * 64 + w * 16 + lc) * DKH;
  bf16x8 qf0 = *(const bf16x8*)(Qb + lh * 8);
  bf16x8 qf1 = *(const bf16x8*)(Qb + lh * 8 + 32);

  f32x4 oacc[4];
  #pragma unroll
  for (int i = 0; i < 4; ++i) oacc[i] = fzero;
  float mrow = -1e30f, lsum = 0.f;
  unsigned short* psw = &Ps[w][0];

  // QK^T for tile in buf; S^T = K Q^T (A = K rows, B = Q cols)
  auto QK = [&](int cur, f32x4 (&sacc)[4]) {
    __builtin_amdgcn_s_setprio(1);
    #pragma unroll
    for (int nf = 0; nf < 4; ++nf) {
      const int row = nf * 16 + lc;
      bf16x8 kf0 = *(const bf16x8*)(&Ks[cur][row * 64 + ((lh) ^ (row & 7)) * 8]);
      bf16x8 kf1 = *(const bf16x8*)(&Ks[cur][row * 64 + ((lh + 4) ^ (row & 7)) * 8]);
      sacc[nf] = __builtin_amdgcn_mfma_f32_16x16x32_bf16(kf0, qf0, fzero, 0, 0, 0);
      sacc[nf] = __builtin_amdgcn_mfma_f32_16x16x32_bf16(kf1, qf1, sacc[nf], 0, 0, 0);
    }
    __builtin_amdgcn_s_setprio(0);
  };

  // softmax (exp2 domain) + P pack into per-wave LDS; MASK only on diagonal
  auto SM = [&](f32x4 (&sacc)[4], bool domask, int t) {
    float sv[4][4];
    float tm = -1e30f;
    if (domask) {
      const int kv0 = t * 64;
      const int qlane = qt * 64 + w * 16 + lc;
      #pragma unroll
      for (int nf = 0; nf < 4; ++nf)
        #pragma unroll
        for (int r = 0; r < 4; ++r) {
          float x = sacc[nf][r];
          if ((kv0 + nf * 16 + lh * 4 + r) > qlane) x = -1e30f;
          sv[nf][r] = x;
          tm = fmaxf(tm, x);
        }
    } else {
      #pragma unroll
      for (int nf = 0; nf < 4; ++nf)
        #pragma unroll
        for (int r = 0; r < 4; ++r) {
          sv[nf][r] = sacc[nf][r];
          tm = fmaxf(tm, sacc[nf][r]);
        }
    }
    tm = fmaxf(tm, __shfl_xor(tm, 16));
    tm = fmaxf(tm, __shfl_xor(tm, 32));
    // defer-max: skip rescale while max growth <= 8 (P bounded by 2^8)
    if (!__all(tm <= mrow + 8.f)) {
      float mn = fmaxf(mrow, tm);
      float alpha = exp2f(mrow - mn);
      mrow = mn;
      lsum *= alpha;
      #pragma unroll
      for (int r = 0; r < 4; ++r) {
        float ar = __shfl(alpha, lh * 4 + r);
        #pragma unroll
        for (int df = 0; df < 4; ++df) oacc[df][r] *= ar;
      }
    }
    float rs = 0.f;
    #pragma unroll
    for (int nf = 0; nf < 4; ++nf)
      #pragma unroll
      for (int r = 0; r < 4; ++r) {
        float p = exp2f(sv[nf][r] - mrow);
        sv[nf][r] = p;
        rs += p;
      }
    lsum += rs;
    #pragma unroll
    for (int nf = 0; nf < 4; ++nf) {
      uint32_t u0, u1;
      asm("v_cvt_pk_bf16_f32 %0, %1, %2" : "=v"(u0) : "v"(sv[nf][0]), "v"(sv[nf][1]));
      asm("v_cvt_pk_bf16_f32 %0, %1, %2" : "=v"(u1) : "v"(sv[nf][2]), "v"(sv[nf][3]));
      int swz = (nf * 2 + (lh >> 1)) ^ (lc & 7);
      uint32_t* p = (uint32_t*)&psw[lc * 64 + swz * 8 + (lh & 1) * 4];
      p[0] = u0; p[1] = u1;
    }
  };

  auto PV = [&](int cur) {
    __builtin_amdgcn_s_setprio(1);
    #pragma unroll
    for (int c = 0; c < 2; ++c) {
      bf16x8 pf = *(const bf16x8*)(&psw[lc * 64 + ((c * 4 + lh) ^ (lc & 7)) * 8]);
      #pragma unroll
      for (int df = 0; df < 4; ++df) {
        const int row = df * 16 + lc;
        bf16x8 vf = *(const bf16x8*)(&Vs[cur][row * 64 + ((c * 4 + lh) ^ (row & 7)) * 8]);
        oacc[df] = __builtin_amdgcn_mfma_f32_16x16x32_bf16(pf, vf, oacc[df], 0, 0, 0);
      }
    }
    __builtin_amdgcn_s_setprio(0);
  };

  STAGE(0, 0);
  for (int t = 0; t < qt; ++t) {          // mask-free main loop
    const int cur = t & 1;
    asm volatile("s_waitcnt vmcnt(0)" ::: "memory");
    __builtin_amdgcn_s_barrier();
    f32x4 sacc[4];
    QK(cur, sacc);
    STAGE(t + 1, cur ^ 1);                // prefetch hides under softmax+PV
    SM(sacc, false, t);
    PV(cur);
  }
  {                                        // peeled diagonal tile t == qt
    const int cur = qt & 1;
    asm volatile("s_waitcnt vmcnt(0)" ::: "memory");
    __builtin_amdgcn_s_barrier();
    f32x4 sacc[4];
    QK(cur, sacc);
    SM(sacc, true, qt);
    PV(cur);
  }

  // group-sum lsum (alpha history identical across the 4 lanes per q-row)
  lsum += __shfl_xor(lsum, 16);
  lsum += __shfl_xor(lsum, 32);
  const int q0 = qt * 64;
  #pragma unroll
  for (int r = 0; r < 4; ++r) {
    float ls = __shfl(lsum, lh * 4 + r);
    float inv = 1.f / ls;
    const int q = q0 + w * 16 + lh * 4 + r;
    #pragma unroll
    for (int df = 0; df < 4; ++df) {
      const int d = h * 64 + df * 16 + lc;
      comb[((size_t)(b * SS + q)) * DMODEL + d] = f2bf(oacc[df][r] * inv);
    }
  }
}

// ---- output projection -----------------------------------------------------
__global__ __launch_bounds__(256) void gemm_out(
    const unsigned short* __restrict__ Cb,
    const unsigned short* __restrict__ Wob,
    float* __restrict__ out)
{
  __shared__ unsigned short As[BM * BK], Bs[BN * BK];
  const int m0 = blockIdx.x * BM, n0 = blockIdx.y * BN;
  f32x4 acc[4][4];
  gemm_tile(Cb, Wob, m0, n0, DMODEL, As, Bs, acc);
  const int lane = threadIdx.x & 63;
  const int w    = threadIdx.x >> 6;
  const int wr   = w >> 1, wc = w & 1;
  const int cb   = lane & 15, rb = (lane >> 4) * 4;
  #pragma unroll
  for (int mi = 0; mi < 4; ++mi)
    #pragma unroll
    for (int ni = 0; ni < 4; ++ni)
      #pragma unroll
      for (int r = 0; r < 4; ++r) {
        int m = m0 + wr * 64 + mi * 16 + rb + r;
        int n = n0 + wc * 64 + ni * 16 + cb;
        out[(size_t)m * DMODEL + n] = acc[mi][ni][r];
      }
}

extern "C" void kernel_launch(void* const* d_in, const int* in_sizes, int n_in,
                              void* d_out, int out_size, void* d_ws, size_t ws_size,
                              hipStream_t stream) {
  (void)in_sizes; (void)n_in; (void)out_size; (void)ws_size;
  const float* X    = (const float*)d_in[0];
  const int*   tpos = (const int*)d_in[1];
  const float* Wq   = (const float*)d_in[2];
  const float* Wk   = (const float*)d_in[3];
  const float* Wv   = (const float*)d_in[4];
  const float* Wo   = (const float*)d_in[5];
  float* out = (float*)d_out;

  uint8_t* ws = (uint8_t*)d_ws;
  const size_t SZ_X = (size_t)MTOT * DMODEL * 2;      // 8 MB
  const size_t SZ_W = (size_t)DMODEL * DMODEL * 2;    // 2 MB
  const size_t SZ_H = (size_t)BB * NH * SS * DKH * 2; // 8 MB
  unsigned short* Xb   = (unsigned short*)(ws);
  unsigned short* Wqb  = (unsigned short*)(ws + SZ_X);
  unsigned short* Wkb  = (unsigned short*)(ws + SZ_X + SZ_W);
  unsigned short* Wvb  = (unsigned short*)(ws + SZ_X + 2 * SZ_W);
  unsigned short* Wob  = (unsigned short*)(ws + SZ_X + 3 * SZ_W);
  unsigned short* Qh   = (unsigned short*)(ws + SZ_X + 4 * SZ_W);
  unsigned short* Kh   = (unsigned short*)(ws + SZ_X + 4 * SZ_W + SZ_H);
  unsigned short* Vt   = (unsigned short*)(ws + SZ_X + 4 * SZ_W + 2 * SZ_H);
  unsigned short* comb = Xb;  // Xb dead after QKV projection

  cvt_bf16<<<dim3(MTOT * DMODEL / 8 / 256), dim3(256), 0, stream>>>(X, Xb, MTOT * DMODEL / 8);
  cvt_w4<<<dim3(DMODEL * DMODEL / 8 / 256, 4), dim3(256), 0, stream>>>(Wq, Wk, Wv, Wo, Wqb);

  gemm_qkv<<<dim3(MTOT / BM, DMODEL / BN, 3), dim3(256), 0, stream>>>(Xb, Wqb, Wkb, Wvb, tpos, Qh, Kh, Vt);
  attn<<<dim3(1024), dim3(256), 0, stream>>>(Qh, Kh, Vt, comb);
  gemm_out<<<dim3(MTOT / BM, DMODEL / BN), dim3(256), 0, stream>>>(comb, Wob, out);
}

// Round 8
// 121.360 us; speedup vs baseline: 3.4741x; 1.0892x over previous
//
#include <hip/hip_runtime.h>
#include <hip/hip_bf16.h>
#include <stdint.h>

#define DMODEL 1024
#define NH 16
#define DKH 64
#define BB 2
#define SS 2048
#define MTOT (BB*SS)   // 4096

#define BM 128
#define BK 32
#define TP 136   // padded LDS tile stride (elems): 272B rows, 16B-aligned

using f32x4  = __attribute__((ext_vector_type(4))) float;
using bf16x8 = __attribute__((ext_vector_type(8))) __bf16;

// async global->LDS, 16B per lane. LDS dest must be wave-uniform base + lane*16.
#define GLL(g, l) __builtin_amdgcn_global_load_lds( \
    (const __attribute__((address_space(1))) unsigned int*)(g), \
    (__attribute__((address_space(3))) unsigned int*)(l), 16, 0, 0)

__device__ __forceinline__ unsigned short f2bf(float f) {
  union { float f; uint32_t u; } v; v.f = f;
  uint32_t r = v.u + 0x7FFFu + ((v.u >> 16) & 1u);
  return (unsigned short)(r >> 16);
}

__global__ __launch_bounds__(256) void cvt_bf16(const float* __restrict__ src,
                                                unsigned short* __restrict__ dst, int n8) {
  int i = blockIdx.x * blockDim.x + threadIdx.x;
  if (i >= n8) return;
  const float4* s4 = (const float4*)src;
  float4 a = s4[2*i], b = s4[2*i+1];
  uint4 o;
  o.x = (uint32_t)f2bf(a.x) | ((uint32_t)f2bf(a.y) << 16);
  o.y = (uint32_t)f2bf(a.z) | ((uint32_t)f2bf(a.w) << 16);
  o.z = (uint32_t)f2bf(b.x) | ((uint32_t)f2bf(b.y) << 16);
  o.w = (uint32_t)f2bf(b.z) | ((uint32_t)f2bf(b.w) << 16);
  *(uint4*)(dst + (size_t)i * 8) = o;
}

// all 4 weight matrices in one launch; dst segments are contiguous in ws
__global__ __launch_bounds__(256) void cvt_w4(const float* __restrict__ w0,
                                              const float* __restrict__ w1,
                                              const float* __restrict__ w2,
                                              const float* __restrict__ w3,
                                              unsigned short* __restrict__ dst) {
  const int zz = blockIdx.y;
  const float* src = (zz == 0) ? w0 : (zz == 1) ? w1 : (zz == 2) ? w2 : w3;
  int i = blockIdx.x * blockDim.x + threadIdx.x;   // 0 .. 131071
  const float4* s4 = (const float4*)src;
  float4 a = s4[2*i], b = s4[2*i+1];
  uint4 o;
  o.x = (uint32_t)f2bf(a.x) | ((uint32_t)f2bf(a.y) << 16);
  o.y = (uint32_t)f2bf(a.z) | ((uint32_t)f2bf(a.w) << 16);
  o.z = (uint32_t)f2bf(b.x) | ((uint32_t)f2bf(b.y) << 16);
  o.w = (uint32_t)f2bf(b.z) | ((uint32_t)f2bf(b.w) << 16);
  *(uint4*)(dst + (size_t)zz * DMODEL * DMODEL + (size_t)i * 8) = o;
}

// ---- pipelined double-buffered NT-GEMM mainloop ----------------------------
// A [M,K], Bw [N,K] bf16 row-major. Tile BM x (NI*32). __syncthreads() per
// K-step (full fence: no cross-wave LDS races); STAGE(t+1) issued at the TOP
// of iteration t so its HBM/L2 latency hides under the ds_read+MFMA phase.
// LDS rows 64B = 4 x 16B chunks, swizzled chunk ^= (row>>1)&3 (8-way -> 2-way).
// Loop ends with __syncthreads(): caller may reuse LDS immediately.
template<int NI>
__device__ __forceinline__ void gemm_pipe(
    const unsigned short* __restrict__ A,
    const unsigned short* __restrict__ Bw,
    int m0, int n0, int K,
    unsigned short* As, unsigned short* Bs,   // dbuf: As 2*BM*BK, Bs 2*NI*32*BK
    f32x4 (&acc)[4][NI])
{
  const int BNl = NI * 32;
  const int tid = threadIdx.x;
  const int lane = tid & 63;
  const int w = tid >> 6;
  const int wr = w >> 1, wc = w & 1;
  const int lrow = lane & 15;
  const int g = lane >> 4;            // 16B chunk index within a 32-elem row

  const f32x4 fzero = {0.f, 0.f, 0.f, 0.f};
  #pragma unroll
  for (int i = 0; i < 4; ++i)
    #pragma unroll
    for (int j = 0; j < NI; ++j)
      acc[i][j] = fzero;

  const int nk = K / BK;

  auto STAGE = [&](int k0, int buf) {
    #pragma unroll
    for (int c = 0; c < 2; ++c) {       // A: 512 chunks, 2/thread
      int i = tid + c * 256;
      int row = i >> 2, cc = i & 3;
      int sc = cc ^ ((row >> 1) & 3);
      GLL(A + (size_t)(m0 + row) * K + k0 + sc * 8, As + buf * (BM * BK) + i * 8);
    }
    #pragma unroll
    for (int c = 0; c < NI / 2; ++c) {  // B: NI*128 chunks
      int i = tid + c * 256;
      int row = i >> 2, cc = i & 3;
      int sc = cc ^ ((row >> 1) & 3);
      GLL(Bw + (size_t)(n0 + row) * K + k0 + sc * 8, Bs + buf * (BNl * BK) + i * 8);
    }
  };

  STAGE(0, 0);
  __syncthreads();                      // stage(0) landed (vmcnt drained)
  for (int t = 0; t < nk; ++t) {
    const int cur = t & 1;
    if (t + 1 < nk) STAGE((t + 1) * BK, cur ^ 1);   // prefetch under compute

    const unsigned short* Ab = As + cur * (BM * BK);
    const unsigned short* Bb = Bs + cur * (BNl * BK);
    bf16x8 af[4], bfr[NI];
    #pragma unroll
    for (int mi = 0; mi < 4; ++mi) {
      int row = wr * 64 + mi * 16 + lrow;
      af[mi] = *(const bf16x8*)(Ab + row * BK + (g ^ ((row >> 1) & 3)) * 8);
    }
    #pragma unroll
    for (int ni = 0; ni < NI; ++ni) {
      int row = wc * (NI * 16) + ni * 16 + lrow;
      bfr[ni] = *(const bf16x8*)(Bb + row * BK + (g ^ ((row >> 1) & 3)) * 8);
    }
    #pragma unroll
    for (int mi = 0; mi < 4; ++mi)
      #pragma unroll
      for (int ni = 0; ni < NI; ++ni)
        acc[mi][ni] = __builtin_amdgcn_mfma_f32_16x16x32_bf16(af[mi], bfr[ni], acc[mi][ni], 0, 0, 0);

    __syncthreads();   // stage(t+1) landed; all reads of buf[cur] complete
  }
}

// ---- fused QKV projection + RoPE + head-split store ------------------------
// B = [Wq;Wk;Wv] rows 0..3071. Q pre-scaled by 0.125*log2(e) (exp2-domain attn).
__global__ __launch_bounds__(256) void gemm_qkv(
    const unsigned short* __restrict__ Xb,
    const unsigned short* __restrict__ Wf,   // [3072][1024]
    const int* __restrict__ tpos,
    unsigned short* __restrict__ Qh,    // [B,H,S,64]
    unsigned short* __restrict__ Kh,    // [B,H,S,64]
    unsigned short* __restrict__ Vt)    // [B,H,64,S]
{
  __shared__ __align__(16) unsigned char smraw[BM * TP * 2];  // 34816 B
  unsigned short* sm = (unsigned short*)smraw;
  unsigned short* As = sm;               // 2*4096 elems
  unsigned short* Bs = sm + 2 * BM * BK; // 2*4096 elems

  const int m0 = blockIdx.x * BM;
  const int n0 = blockIdx.y * 128;       // 0..2944
  const int z  = n0 >> 10;
  const int nloc = n0 & 1023;

  f32x4 acc[4][4];
  gemm_pipe<4>(Xb, Wf, m0, n0, DMODEL, As, Bs, acc);
  // gemm_pipe ends with __syncthreads -> safe to reuse sm

  const int tid  = threadIdx.x;
  const int lane = tid & 63;
  const int w    = tid >> 6;
  const int wr   = w >> 1, wc = w & 1;
  const int cb   = lane & 15, rb = (lane >> 4) * 4;

  if (z < 2) {
    #pragma unroll
    for (int mi = 0; mi < 4; ++mi)
      #pragma unroll
      for (int ni = 0; ni < 4; ++ni)
        #pragma unroll
        for (int r = 0; r < 4; ++r)
          sm[(wr * 64 + mi * 16 + rb + r) * TP + wc * 64 + ni * 16 + cb] = f2bf(acc[mi][ni][r]);
  } else {
    #pragma unroll
    for (int mi = 0; mi < 4; ++mi)
      #pragma unroll
      for (int ni = 0; ni < 4; ++ni)
        #pragma unroll
        for (int r = 0; r < 4; ++r)
          sm[(wc * 64 + ni * 16 + cb) * TP + wr * 64 + mi * 16 + rb + r] = f2bf(acc[mi][ni][r]);
  }
  __syncthreads();

  const int b = m0 >> 11;
  const float l2t = 13.28771237954945f / 32.0f;   // log2(10000)/32
  const float qsc = (z == 0) ? 0.18033688011112042f : 1.0f;  // 0.125*log2(e)

  if (z < 2) {
    unsigned short* dst = (z == 0) ? Qh : Kh;
    #pragma unroll
    for (int p = 0; p < 8; ++p) {
      const int m_l = p * 16 + (tid >> 4);
      const int ck  = tid & 15;
      bf16x8 vals = *(const bf16x8*)(sm + m_l * TP + ck * 8);
      const int m = m0 + m_l, s = m & (SS - 1);
      const int pos = tpos[m];
      const int n = nloc + ck * 8, h = n >> 6, dh = n & 63;
      union { unsigned short u[8]; uint4 v; } ov;
      #pragma unroll
      for (int e = 0; e < 4; ++e) {
        float x1 = (float)vals[2 * e], x2 = (float)vals[2 * e + 1];
        int j = (dh >> 1) + e;
        float ang = (float)pos * exp2f(-(float)j * l2t);
        float sn, cs;
        sincosf(ang, &sn, &cs);
        sn *= qsc; cs *= qsc;
        ov.u[2 * e]     = f2bf(x1 * cs - x2 * sn);
        ov.u[2 * e + 1] = f2bf(x1 * sn + x2 * cs);
      }
      *(uint4*)(dst + ((size_t)(b * NH + h) * SS + s) * DKH + dh) = ov.v;
    }
  } else {
    #pragma unroll
    for (int p = 0; p < 8; ++p) {
      const int n_l = p * 16 + (tid >> 4);
      const int ck  = tid & 15;
      bf16x8 vals = *(const bf16x8*)(sm + n_l * TP + ck * 8);
      const int n = nloc + n_l, h = n >> 6, dh = n & 63;
      const int m = m0 + ck * 8, s = m & (SS - 1);
      *(bf16x8*)(Vt + ((size_t)(b * NH + h) * DKH + dh) * SS + s) = vals;
    }
  }
}

// ---- flash attention (causal), single-chain, occupancy-optimized -----------
__global__ __launch_bounds__(256) void attn(
    const unsigned short* __restrict__ Qh,
    const unsigned short* __restrict__ Kh,
    const unsigned short* __restrict__ Vt,
    unsigned short* __restrict__ comb)  // [B,S,1024]
{
  __shared__ unsigned short Ks[2][64 * 64];  // [kv][d], chunk^row swizzled
  __shared__ unsigned short Vs[2][64 * 64];  // [d][kv], chunk^row swizzled
  __shared__ unsigned short Ps[4][16 * 64];  // per-wave P, swizzled

  const int idx = blockIdx.x;          // 0..1023
  const int u = idx & 255, v = idx >> 8;
  const int j = u >> 3;
  const int bh = (u & 7) + 8 * v;
  const int qt = (v & 1) ? j : 31 - j; // per-CU resident set {j,31-j,j,31-j}

  const int tid = threadIdx.x, lane = tid & 63, w = tid >> 6;
  const int lc = lane & 15, lh = lane >> 4;

  const unsigned short* kb = Kh + (size_t)bh * SS * DKH;
  const unsigned short* vb = Vt + (size_t)bh * DKH * SS;
  const int b = bh >> 4, h = bh & 15;
  const f32x4 fzero = {0.f, 0.f, 0.f, 0.f};

  auto STAGE = [&](int t, int buf) {
    const int kv0 = t * 64;
    #pragma unroll
    for (int c = 0; c < 2; ++c) {
      int i = tid + c * 256;             // 512 x 16B chunks
      int row = i >> 3, pc = i & 7;
      int sc = pc ^ (row & 7);           // inverse swizzle on global source
      GLL(kb + (size_t)(kv0 + row) * DKH + sc * 8, &Ks[buf][i * 8]);
      GLL(vb + (size_t)row * SS + kv0 + sc * 8, &Vs[buf][i * 8]);
    }
  };

  const unsigned short* Qb = Qh + ((size_t)bh * SS + qt * 64 + w * 16 + lc) * DKH;
  bf16x8 qf0 = *(const bf16x8*)(Qb + lh * 8);
  bf16x8 qf1 = *(const bf16x8*)(Qb + lh * 8 + 32);

  f32x4 oacc[4];
  #pragma unroll
  for (int i = 0; i < 4; ++i) oacc[i] = fzero;
  float mrow = -1e30f, lsum = 0.f;
  unsigned short* psw = &Ps[w][0];

  auto QK = [&](int cur, f32x4 (&sacc)[4]) {
    __builtin_amdgcn_s_setprio(1);
    #pragma unroll
    for (int nf = 0; nf < 4; ++nf) {
      const int row = nf * 16 + lc;
      bf16x8 kf0 = *(const bf16x8*)(&Ks[cur][row * 64 + ((lh) ^ (row & 7)) * 8]);
      bf16x8 kf1 = *(const bf16x8*)(&Ks[cur][row * 64 + ((lh + 4) ^ (row & 7)) * 8]);
      sacc[nf] = __builtin_amdgcn_mfma_f32_16x16x32_bf16(kf0, qf0, fzero, 0, 0, 0);
      sacc[nf] = __builtin_amdgcn_mfma_f32_16x16x32_bf16(kf1, qf1, sacc[nf], 0, 0, 0);
    }
    __builtin_amdgcn_s_setprio(0);
  };

  auto SM = [&](f32x4 (&sacc)[4], bool domask, int t) {
    float sv[4][4];
    float tm = -1e30f;
    if (domask) {
      const int kv0 = t * 64;
      const int qlane = qt * 64 + w * 16 + lc;
      #pragma unroll
      for (int nf = 0; nf < 4; ++nf)
        #pragma unroll
        for (int r = 0; r < 4; ++r) {
          float x = sacc[nf][r];
          if ((kv0 + nf * 16 + lh * 4 + r) > qlane) x = -1e30f;
          sv[nf][r] = x;
          tm = fmaxf(tm, x);
        }
    } else {
      #pragma unroll
      for (int nf = 0; nf < 4; ++nf)
        #pragma unroll
        for (int r = 0; r < 4; ++r) {
          sv[nf][r] = sacc[nf][r];
          tm = fmaxf(tm, sacc[nf][r]);
        }
    }
    tm = fmaxf(tm, __shfl_xor(tm, 16));
    tm = fmaxf(tm, __shfl_xor(tm, 32));
    if (!__all(tm <= mrow + 8.f)) {
      float mn = fmaxf(mrow, tm);
      float alpha = exp2f(mrow - mn);
      mrow = mn;
      lsum *= alpha;
      #pragma unroll
      for (int r = 0; r < 4; ++r) {
        float ar = __shfl(alpha, lh * 4 + r);
        #pragma unroll
        for (int df = 0; df < 4; ++df) oacc[df][r] *= ar;
      }
    }
    float rs = 0.f;
    #pragma unroll
    for (int nf = 0; nf < 4; ++nf)
      #pragma unroll
      for (int r = 0; r < 4; ++r) {
        float p = exp2f(sv[nf][r] - mrow);
        sv[nf][r] = p;
        rs += p;
      }
    lsum += rs;
    #pragma unroll
    for (int nf = 0; nf < 4; ++nf) {
      uint32_t u0, u1;
      asm("v_cvt_pk_bf16_f32 %0, %1, %2" : "=v"(u0) : "v"(sv[nf][0]), "v"(sv[nf][1]));
      asm("v_cvt_pk_bf16_f32 %0, %1, %2" : "=v"(u1) : "v"(sv[nf][2]), "v"(sv[nf][3]));
      int swz = (nf * 2 + (lh >> 1)) ^ (lc & 7);
      uint32_t* p = (uint32_t*)&psw[lc * 64 + swz * 8 + (lh & 1) * 4];
      p[0] = u0; p[1] = u1;
    }
  };

  auto PV = [&](int cur) {
    __builtin_amdgcn_s_setprio(1);
    #pragma unroll
    for (int c = 0; c < 2; ++c) {
      bf16x8 pf = *(const bf16x8*)(&psw[lc * 64 + ((c * 4 + lh) ^ (lc & 7)) * 8]);
      #pragma unroll
      for (int df = 0; df < 4; ++df) {
        const int row = df * 16 + lc;
        bf16x8 vf = *(const bf16x8*)(&Vs[cur][row * 64 + ((c * 4 + lh) ^ (row & 7)) * 8]);
        oacc[df] = __builtin_amdgcn_mfma_f32_16x16x32_bf16(pf, vf, oacc[df], 0, 0, 0);
      }
    }
    __builtin_amdgcn_s_setprio(0);
  };

  STAGE(0, 0);
  for (int t = 0; t < qt; ++t) {          // mask-free main loop
    const int cur = t & 1;
    asm volatile("s_waitcnt vmcnt(0)" ::: "memory");
    __builtin_amdgcn_s_barrier();
    f32x4 sacc[4];
    QK(cur, sacc);
    STAGE(t + 1, cur ^ 1);
    SM(sacc, false, t);
    PV(cur);
  }
  {                                        // peeled diagonal tile t == qt
    const int cur = qt & 1;
    asm volatile("s_waitcnt vmcnt(0)" ::: "memory");
    __builtin_amdgcn_s_barrier();
    f32x4 sacc[4];
    QK(cur, sacc);
    SM(sacc, true, qt);
    PV(cur);
  }

  lsum += __shfl_xor(lsum, 16);
  lsum += __shfl_xor(lsum, 32);
  const int q0 = qt * 64;
  #pragma unroll
  for (int r = 0; r < 4; ++r) {
    float ls = __shfl(lsum, lh * 4 + r);
    float inv = 1.f / ls;
    const int q = q0 + w * 16 + lh * 4 + r;
    #pragma unroll
    for (int df = 0; df < 4; ++df) {
      const int d = h * 64 + df * 16 + lc;
      comb[((size_t)(b * SS + q)) * DMODEL + d] = f2bf(oacc[df][r] * inv);
    }
  }
}

// ---- output projection: 128x64 tiles, coalesced f32 epilogue ---------------
__global__ __launch_bounds__(256) void gemm_out(
    const unsigned short* __restrict__ Cb,
    const unsigned short* __restrict__ Wob,
    float* __restrict__ out)
{
  __shared__ __align__(16) unsigned char smraw[BM * TP * 2];  // 34816 B
  unsigned short* As = (unsigned short*)smraw;        // 2*4096 elems
  unsigned short* Bs = (unsigned short*)smraw + 2 * BM * BK;  // 2*2048 elems
  float* smf = (float*)smraw;                         // [128][68] f32 view

  const int m0 = blockIdx.x * BM, n0 = blockIdx.y * 64;
  f32x4 acc[4][2];
  gemm_pipe<2>(Cb, Wob, m0, n0, DMODEL, As, Bs, acc);
  // gemm_pipe ends with __syncthreads -> safe to reuse LDS

  const int tid  = threadIdx.x;
  const int lane = tid & 63;
  const int w    = tid >> 6;
  const int wr   = w >> 1, wc = w & 1;
  const int cb   = lane & 15, rb = (lane >> 4) * 4;

  #pragma unroll
  for (int mi = 0; mi < 4; ++mi)
    #pragma unroll
    for (int ni = 0; ni < 2; ++ni)
      #pragma unroll
      for (int r = 0; r < 4; ++r)
        smf[(wr * 64 + mi * 16 + rb + r) * 68 + wc * 32 + ni * 16 + cb] = acc[mi][ni][r];
  __syncthreads();

  #pragma unroll
  for (int p = 0; p < 8; ++p) {
    const int row = p * 16 + (tid >> 4);
    const int ck  = tid & 15;
    float4 vv = *(const float4*)(smf + row * 68 + ck * 4);
    *(float4*)(out + (size_t)(m0 + row) * DMODEL + n0 + ck * 4) = vv;
  }
}

extern "C" void kernel_launch(void* const* d_in, const int* in_sizes, int n_in,
                              void* d_out, int out_size, void* d_ws, size_t ws_size,
                              hipStream_t stream) {
  (void)in_sizes; (void)n_in; (void)out_size; (void)ws_size;
  const float* X    = (const float*)d_in[0];
  const int*   tpos = (const int*)d_in[1];
  const float* Wq   = (const float*)d_in[2];
  const float* Wk   = (const float*)d_in[3];
  const float* Wv   = (const float*)d_in[4];
  const float* Wo   = (const float*)d_in[5];
  float* out = (float*)d_out;

  uint8_t* ws = (uint8_t*)d_ws;
  const size_t SZ_X = (size_t)MTOT * DMODEL * 2;      // 8 MB
  const size_t SZ_W = (size_t)DMODEL * DMODEL * 2;    // 2 MB
  const size_t SZ_H = (size_t)BB * NH * SS * DKH * 2; // 8 MB
  unsigned short* Xb   = (unsigned short*)(ws);
  unsigned short* Wqb  = (unsigned short*)(ws + SZ_X);         // [Wq;Wk;Wv;Wo]
  unsigned short* Wob  = (unsigned short*)(ws + SZ_X + 3 * SZ_W);
  unsigned short* Qh   = (unsigned short*)(ws + SZ_X + 4 * SZ_W);
  unsigned short* Kh   = (unsigned short*)(ws + SZ_X + 4 * SZ_W + SZ_H);
  unsigned short* Vt   = (unsigned short*)(ws + SZ_X + 4 * SZ_W + 2 * SZ_H);
  unsigned short* comb = Xb;  // Xb dead after QKV projection

  cvt_bf16<<<dim3(MTOT * DMODEL / 8 / 256), dim3(256), 0, stream>>>(X, Xb, MTOT * DMODEL / 8);
  cvt_w4<<<dim3(DMODEL * DMODEL / 8 / 256, 4), dim3(256), 0, stream>>>(Wq, Wk, Wv, Wo, Wqb);

  gemm_qkv<<<dim3(MTOT / BM, 24), dim3(256), 0, stream>>>(Xb, Wqb, tpos, Qh, Kh, Vt);
  attn<<<dim3(1024), dim3(256), 0, stream>>>(Qh, Kh, Vt, comb);
  gemm_out<<<dim3(MTOT / BM, 16), dim3(256), 0, stream>>>(comb, Wob, out);
}

// Round 9
// 116.742 us; speedup vs baseline: 3.6115x; 1.0396x over previous
//
#include <hip/hip_runtime.h>
#include <hip/hip_bf16.h>
#include <stdint.h>

#define DMODEL 1024
#define NH 16
#define DKH 64
#define BB 2
#define SS 2048
#define MTOT (BB*SS)   // 4096

#define BM 128
#define BK 32
#define TP 136   // padded LDS tile stride (elems): 272B rows, 16B-aligned

using f32x4  = __attribute__((ext_vector_type(4))) float;
using bf16x8 = __attribute__((ext_vector_type(8))) __bf16;

// async global->LDS, 16B per lane. LDS dest must be wave-uniform base + lane*16.
#define GLL(g, l) __builtin_amdgcn_global_load_lds( \
    (const __attribute__((address_space(1))) unsigned int*)(g), \
    (__attribute__((address_space(3))) unsigned int*)(l), 16, 0, 0)

__device__ __forceinline__ unsigned short f2bf(float f) {
  union { float f; uint32_t u; } v; v.f = f;
  uint32_t r = v.u + 0x7FFFu + ((v.u >> 16) & 1u);
  return (unsigned short)(r >> 16);
}

__global__ __launch_bounds__(256) void cvt_bf16(const float* __restrict__ src,
                                                unsigned short* __restrict__ dst, int n8) {
  int i = blockIdx.x * blockDim.x + threadIdx.x;
  if (i >= n8) return;
  const float4* s4 = (const float4*)src;
  float4 a = s4[2*i], b = s4[2*i+1];
  uint4 o;
  o.x = (uint32_t)f2bf(a.x) | ((uint32_t)f2bf(a.y) << 16);
  o.y = (uint32_t)f2bf(a.z) | ((uint32_t)f2bf(a.w) << 16);
  o.z = (uint32_t)f2bf(b.x) | ((uint32_t)f2bf(b.y) << 16);
  o.w = (uint32_t)f2bf(b.z) | ((uint32_t)f2bf(b.w) << 16);
  *(uint4*)(dst + (size_t)i * 8) = o;
}

// all 4 weight matrices in one launch; dst segments are contiguous in ws
__global__ __launch_bounds__(256) void cvt_w4(const float* __restrict__ w0,
                                              const float* __restrict__ w1,
                                              const float* __restrict__ w2,
                                              const float* __restrict__ w3,
                                              unsigned short* __restrict__ dst) {
  const int zz = blockIdx.y;
  const float* src = (zz == 0) ? w0 : (zz == 1) ? w1 : (zz == 2) ? w2 : w3;
  int i = blockIdx.x * blockDim.x + threadIdx.x;   // 0 .. 131071
  const float4* s4 = (const float4*)src;
  float4 a = s4[2*i], b = s4[2*i+1];
  uint4 o;
  o.x = (uint32_t)f2bf(a.x) | ((uint32_t)f2bf(a.y) << 16);
  o.y = (uint32_t)f2bf(a.z) | ((uint32_t)f2bf(a.w) << 16);
  o.z = (uint32_t)f2bf(b.x) | ((uint32_t)f2bf(b.y) << 16);
  o.w = (uint32_t)f2bf(b.z) | ((uint32_t)f2bf(b.w) << 16);
  *(uint4*)(dst + (size_t)zz * DMODEL * DMODEL + (size_t)i * 8) = o;
}

// ---- 3-buffer, 2-ahead pipelined NT-GEMM mainloop (T3/T4: counted vmcnt) ---
// A [M,K], Bw [N,K] bf16 row-major. Tile BM x (NI*32).
// Invariant at iteration t's wait: outstanding vm-ops = stage(t) + stage(t+1).
// s_waitcnt vmcnt(VMO) -> stage(t) landed, stage(t+1) still in flight (never
// drain to 0 in-loop). lgkmcnt(0) retires this wave's ds_reads of the buffer
// STAGE(t+2) will overwrite. sched_barrier(0) brackets the s_barrier so the
// compiler cannot hoist ds_reads/GLLs across it (rule #18 / R7 race).
// LDS rows 64B = 4 x 16B chunks, swizzled chunk ^= (row>>1)&3 (8-way -> 2-way).
// Exits with __syncthreads(): caller may reuse the LDS immediately.
template<int NI>
__device__ __forceinline__ void gemm_pipe(
    const unsigned short* __restrict__ A,
    const unsigned short* __restrict__ Bw,
    int m0, int n0, int K,
    unsigned short* As, unsigned short* Bs,   // 3 bufs: As 3*BM*BK, Bs 3*NI*32*BK
    f32x4 (&acc)[4][NI])
{
  const int BNl = NI * 32;
  const int tid = threadIdx.x;
  const int lane = tid & 63;
  const int w = tid >> 6;
  const int wr = w >> 1, wc = w & 1;
  const int lrow = lane & 15;
  const int g = lane >> 4;            // 16B chunk index within a 32-elem row

  const f32x4 fzero = {0.f, 0.f, 0.f, 0.f};
  #pragma unroll
  for (int i = 0; i < 4; ++i)
    #pragma unroll
    for (int j = 0; j < NI; ++j)
      acc[i][j] = fzero;

  const int nk = K / BK;

  auto STAGE = [&](int t, int buf) {
    const int k0 = t * BK;
    #pragma unroll
    for (int c = 0; c < 2; ++c) {       // A: 512 chunks, 2/thread
      int i = tid + c * 256;
      int row = i >> 2, cc = i & 3;
      int sc = cc ^ ((row >> 1) & 3);
      GLL(A + (size_t)(m0 + row) * K + k0 + sc * 8, As + buf * (BM * BK) + i * 8);
    }
    #pragma unroll
    for (int c = 0; c < NI / 2; ++c) {  // B: NI*128 chunks
      int i = tid + c * 256;
      int row = i >> 2, cc = i & 3;
      int sc = cc ^ ((row >> 1) & 3);
      GLL(Bw + (size_t)(n0 + row) * K + k0 + sc * 8, Bs + buf * (BNl * BK) + i * 8);
    }
  };

  STAGE(0, 0);
  STAGE(1, 1);
  for (int t = 0; t < nk; ++t) {
    const int cur = t % 3;
    if (t + 1 < nk) {
      // wait stage(t) only; stage(t+1)'s VMO ops stay in flight
      if constexpr (NI == 4) asm volatile("s_waitcnt vmcnt(4) lgkmcnt(0)" ::: "memory");
      else                   asm volatile("s_waitcnt vmcnt(3) lgkmcnt(0)" ::: "memory");
    } else {
      asm volatile("s_waitcnt vmcnt(0) lgkmcnt(0)" ::: "memory");
    }
    __builtin_amdgcn_sched_barrier(0);
    __builtin_amdgcn_s_barrier();
    __builtin_amdgcn_sched_barrier(0);
    if (t + 2 < nk) STAGE(t + 2, (t + 2) % 3);   // overwrites buffer read at t-1

    const unsigned short* Ab = As + cur * (BM * BK);
    const unsigned short* Bb = Bs + cur * (BNl * BK);
    bf16x8 af[4], bfr[NI];
    #pragma unroll
    for (int mi = 0; mi < 4; ++mi) {
      int row = wr * 64 + mi * 16 + lrow;
      af[mi] = *(const bf16x8*)(Ab + row * BK + (g ^ ((row >> 1) & 3)) * 8);
    }
    #pragma unroll
    for (int ni = 0; ni < NI; ++ni) {
      int row = wc * (NI * 16) + ni * 16 + lrow;
      bfr[ni] = *(const bf16x8*)(Bb + row * BK + (g ^ ((row >> 1) & 3)) * 8);
    }
    #pragma unroll
    for (int mi = 0; mi < 4; ++mi)
      #pragma unroll
      for (int ni = 0; ni < NI; ++ni)
        acc[mi][ni] = __builtin_amdgcn_mfma_f32_16x16x32_bf16(af[mi], bfr[ni], acc[mi][ni], 0, 0, 0);
  }
  __syncthreads();   // all waves done with the K-loop; LDS reusable
}

// ---- fused QKV projection + RoPE + head-split store ------------------------
// B = [Wq;Wk;Wv] rows 0..3071. Q pre-scaled by 0.125*log2(e) (exp2-domain attn).
__global__ __launch_bounds__(256) void gemm_qkv(
    const unsigned short* __restrict__ Xb,
    const unsigned short* __restrict__ Wf,   // [3072][1024]
    const int* __restrict__ tpos,
    unsigned short* __restrict__ Qh,    // [B,H,S,64]
    unsigned short* __restrict__ Kh,    // [B,H,S,64]
    unsigned short* __restrict__ Vt)    // [B,H,64,S]
{
  __shared__ __align__(16) unsigned char smraw[49152];  // 3-buf staging / epilogue
  unsigned short* sm = (unsigned short*)smraw;
  unsigned short* As = sm;                // 3*4096 elems
  unsigned short* Bs = sm + 3 * BM * BK;  // 3*4096 elems

  const int m0 = blockIdx.x * BM;
  const int n0 = blockIdx.y * 128;       // 0..2944
  const int z  = n0 >> 10;
  const int nloc = n0 & 1023;

  f32x4 acc[4][4];
  gemm_pipe<4>(Xb, Wf, m0, n0, DMODEL, As, Bs, acc);
  // gemm_pipe ends with __syncthreads -> safe to reuse sm

  const int tid  = threadIdx.x;
  const int lane = tid & 63;
  const int w    = tid >> 6;
  const int wr   = w >> 1, wc = w & 1;
  const int cb   = lane & 15, rb = (lane >> 4) * 4;

  if (z < 2) {
    #pragma unroll
    for (int mi = 0; mi < 4; ++mi)
      #pragma unroll
      for (int ni = 0; ni < 4; ++ni)
        #pragma unroll
        for (int r = 0; r < 4; ++r)
          sm[(wr * 64 + mi * 16 + rb + r) * TP + wc * 64 + ni * 16 + cb] = f2bf(acc[mi][ni][r]);
  } else {
    #pragma unroll
    for (int mi = 0; mi < 4; ++mi)
      #pragma unroll
      for (int ni = 0; ni < 4; ++ni)
        #pragma unroll
        for (int r = 0; r < 4; ++r)
          sm[(wc * 64 + ni * 16 + cb) * TP + wr * 64 + mi * 16 + rb + r] = f2bf(acc[mi][ni][r]);
  }
  __syncthreads();

  const int b = m0 >> 11;
  const float l2t = 13.28771237954945f / 32.0f;   // log2(10000)/32
  const float qsc = (z == 0) ? 0.18033688011112042f : 1.0f;  // 0.125*log2(e)

  if (z < 2) {
    unsigned short* dst = (z == 0) ? Qh : Kh;
    #pragma unroll
    for (int p = 0; p < 8; ++p) {
      const int m_l = p * 16 + (tid >> 4);
      const int ck  = tid & 15;
      bf16x8 vals = *(const bf16x8*)(sm + m_l * TP + ck * 8);
      const int m = m0 + m_l, s = m & (SS - 1);
      const int pos = tpos[m];
      const int n = nloc + ck * 8, h = n >> 6, dh = n & 63;
      union { unsigned short u[8]; uint4 v; } ov;
      #pragma unroll
      for (int e = 0; e < 4; ++e) {
        float x1 = (float)vals[2 * e], x2 = (float)vals[2 * e + 1];
        int j = (dh >> 1) + e;
        float ang = (float)pos * exp2f(-(float)j * l2t);
        float sn, cs;
        sincosf(ang, &sn, &cs);
        sn *= qsc; cs *= qsc;
        ov.u[2 * e]     = f2bf(x1 * cs - x2 * sn);
        ov.u[2 * e + 1] = f2bf(x1 * sn + x2 * cs);
      }
      *(uint4*)(dst + ((size_t)(b * NH + h) * SS + s) * DKH + dh) = ov.v;
    }
  } else {
    #pragma unroll
    for (int p = 0; p < 8; ++p) {
      const int n_l = p * 16 + (tid >> 4);
      const int ck  = tid & 15;
      bf16x8 vals = *(const bf16x8*)(sm + n_l * TP + ck * 8);
      const int n = nloc + n_l, h = n >> 6, dh = n & 63;
      const int m = m0 + ck * 8, s = m & (SS - 1);
      *(bf16x8*)(Vt + ((size_t)(b * NH + h) * DKH + dh) * SS + s) = vals;
    }
  }
}

// ---- flash attention (causal), single-chain, occupancy-optimized -----------
__global__ __launch_bounds__(256) void attn(
    const unsigned short* __restrict__ Qh,
    const unsigned short* __restrict__ Kh,
    const unsigned short* __restrict__ Vt,
    unsigned short* __restrict__ comb)  // [B,S,1024]
{
  __shared__ unsigned short Ks[2][64 * 64];  // [kv][d], chunk^row swizzled
  __shared__ unsigned short Vs[2][64 * 64];  // [d][kv], chunk^row swizzled
  __shared__ unsigned short Ps[4][16 * 64];  // per-wave P, swizzled

  const int idx = blockIdx.x;          // 0..1023
  const int u = idx & 255, v = idx >> 8;
  const int j = u >> 3;
  const int bh = (u & 7) + 8 * v;
  const int qt = (v & 1) ? j : 31 - j; // per-CU resident set {j,31-j,j,31-j}

  const int tid = threadIdx.x, lane = tid & 63, w = tid >> 6;
  const int lc = lane & 15, lh = lane >> 4;

  const unsigned short* kb = Kh + (size_t)bh * SS * DKH;
  const unsigned short* vb = Vt + (size_t)bh * DKH * SS;
  const int b = bh >> 4, h = bh & 15;
  const f32x4 fzero = {0.f, 0.f, 0.f, 0.f};

  auto STAGE = [&](int t, int buf) {
    const int kv0 = t * 64;
    #pragma unroll
    for (int c = 0; c < 2; ++c) {
      int i = tid + c * 256;             // 512 x 16B chunks
      int row = i >> 3, pc = i & 7;
      int sc = pc ^ (row & 7);           // inverse swizzle on global source
      GLL(kb + (size_t)(kv0 + row) * DKH + sc * 8, &Ks[buf][i * 8]);
      GLL(vb + (size_t)row * SS + kv0 + sc * 8, &Vs[buf][i * 8]);
    }
  };

  const unsigned short* Qb = Qh + ((size_t)bh * SS + qt * 64 + w * 16 + lc) * DKH;
  bf16x8 qf0 = *(const bf16x8*)(Qb + lh * 8);
  bf16x8 qf1 = *(const bf16x8*)(Qb + lh * 8 + 32);

  f32x4 oacc[4];
  #pragma unroll
  for (int i = 0; i < 4; ++i) oacc[i] = fzero;
  float mrow = -1e30f, lsum = 0.f;
  unsigned short* psw = &Ps[w][0];

  auto QK = [&](int cur, f32x4 (&sacc)[4]) {
    __builtin_amdgcn_s_setprio(1);
    #pragma unroll
    for (int nf = 0; nf < 4; ++nf) {
      const int row = nf * 16 + lc;
      bf16x8 kf0 = *(const bf16x8*)(&Ks[cur][row * 64 + ((lh) ^ (row & 7)) * 8]);
      bf16x8 kf1 = *(const bf16x8*)(&Ks[cur][row * 64 + ((lh + 4) ^ (row & 7)) * 8]);
      sacc[nf] = __builtin_amdgcn_mfma_f32_16x16x32_bf16(kf0, qf0, fzero, 0, 0, 0);
      sacc[nf] = __builtin_amdgcn_mfma_f32_16x16x32_bf16(kf1, qf1, sacc[nf], 0, 0, 0);
    }
    __builtin_amdgcn_s_setprio(0);
  };

  auto SM = [&](f32x4 (&sacc)[4], bool domask, int t) {
    float sv[4][4];
    float tm = -1e30f;
    if (domask) {
      const int kv0 = t * 64;
      const int qlane = qt * 64 + w * 16 + lc;
      #pragma unroll
      for (int nf = 0; nf < 4; ++nf)
        #pragma unroll
        for (int r = 0; r < 4; ++r) {
          float x = sacc[nf][r];
          if ((kv0 + nf * 16 + lh * 4 + r) > qlane) x = -1e30f;
          sv[nf][r] = x;
          tm = fmaxf(tm, x);
        }
    } else {
      #pragma unroll
      for (int nf = 0; nf < 4; ++nf)
        #pragma unroll
        for (int r = 0; r < 4; ++r) {
          sv[nf][r] = sacc[nf][r];
          tm = fmaxf(tm, sacc[nf][r]);
        }
    }
    tm = fmaxf(tm, __shfl_xor(tm, 16));
    tm = fmaxf(tm, __shfl_xor(tm, 32));
    if (!__all(tm <= mrow + 8.f)) {
      float mn = fmaxf(mrow, tm);
      float alpha = exp2f(mrow - mn);
      mrow = mn;
      lsum *= alpha;
      #pragma unroll
      for (int r = 0; r < 4; ++r) {
        float ar = __shfl(alpha, lh * 4 + r);
        #pragma unroll
        for (int df = 0; df < 4; ++df) oacc[df][r] *= ar;
      }
    }
    float rs = 0.f;
    #pragma unroll
    for (int nf = 0; nf < 4; ++nf)
      #pragma unroll
      for (int r = 0; r < 4; ++r) {
        float p = exp2f(sv[nf][r] - mrow);
        sv[nf][r] = p;
        rs += p;
      }
    lsum += rs;
    #pragma unroll
    for (int nf = 0; nf < 4; ++nf) {
      uint32_t u0, u1;
      asm("v_cvt_pk_bf16_f32 %0, %1, %2" : "=v"(u0) : "v"(sv[nf][0]), "v"(sv[nf][1]));
      asm("v_cvt_pk_bf16_f32 %0, %1, %2" : "=v"(u1) : "v"(sv[nf][2]), "v"(sv[nf][3]));
      int swz = (nf * 2 + (lh >> 1)) ^ (lc & 7);
      uint32_t* p = (uint32_t*)&psw[lc * 64 + swz * 8 + (lh & 1) * 4];
      p[0] = u0; p[1] = u1;
    }
  };

  auto PV = [&](int cur) {
    __builtin_amdgcn_s_setprio(1);
    #pragma unroll
    for (int c = 0; c < 2; ++c) {
      bf16x8 pf = *(const bf16x8*)(&psw[lc * 64 + ((c * 4 + lh) ^ (lc & 7)) * 8]);
      #pragma unroll
      for (int df = 0; df < 4; ++df) {
        const int row = df * 16 + lc;
        bf16x8 vf = *(const bf16x8*)(&Vs[cur][row * 64 + ((c * 4 + lh) ^ (row & 7)) * 8]);
        oacc[df] = __builtin_amdgcn_mfma_f32_16x16x32_bf16(pf, vf, oacc[df], 0, 0, 0);
      }
    }
    __builtin_amdgcn_s_setprio(0);
  };

  STAGE(0, 0);
  for (int t = 0; t < qt; ++t) {          // mask-free main loop
    const int cur = t & 1;
    asm volatile("s_waitcnt vmcnt(0)" ::: "memory");
    __builtin_amdgcn_s_barrier();
    f32x4 sacc[4];
    QK(cur, sacc);
    STAGE(t + 1, cur ^ 1);
    SM(sacc, false, t);
    PV(cur);
  }
  {                                        // peeled diagonal tile t == qt
    const int cur = qt & 1;
    asm volatile("s_waitcnt vmcnt(0)" ::: "memory");
    __builtin_amdgcn_s_barrier();
    f32x4 sacc[4];
    QK(cur, sacc);
    SM(sacc, true, qt);
    PV(cur);
  }

  lsum += __shfl_xor(lsum, 16);
  lsum += __shfl_xor(lsum, 32);
  const int q0 = qt * 64;
  #pragma unroll
  for (int r = 0; r < 4; ++r) {
    float ls = __shfl(lsum, lh * 4 + r);
    float inv = 1.f / ls;
    const int q = q0 + w * 16 + lh * 4 + r;
    #pragma unroll
    for (int df = 0; df < 4; ++df) {
      const int d = h * 64 + df * 16 + lc;
      comb[((size_t)(b * SS + q)) * DMODEL + d] = f2bf(oacc[df][r] * inv);
    }
  }
}

// ---- output projection: 128x64 tiles, coalesced f32 epilogue ---------------
__global__ __launch_bounds__(256) void gemm_out(
    const unsigned short* __restrict__ Cb,
    const unsigned short* __restrict__ Wob,
    float* __restrict__ out)
{
  __shared__ __align__(16) unsigned char smraw[36864];  // 3-buf staging / epilogue
  unsigned short* As = (unsigned short*)smraw;                // 3*4096 elems
  unsigned short* Bs = (unsigned short*)smraw + 3 * BM * BK;  // 3*2048 elems
  float* smf = (float*)smraw;                                 // [128][68] f32 view

  const int m0 = blockIdx.x * BM, n0 = blockIdx.y * 64;
  f32x4 acc[4][2];
  gemm_pipe<2>(Cb, Wob, m0, n0, DMODEL, As, Bs, acc);
  // gemm_pipe ends with __syncthreads -> safe to reuse LDS

  const int tid  = threadIdx.x;
  const int lane = tid & 63;
  const int w    = tid >> 6;
  const int wr   = w >> 1, wc = w & 1;
  const int cb   = lane & 15, rb = (lane >> 4) * 4;

  #pragma unroll
  for (int mi = 0; mi < 4; ++mi)
    #pragma unroll
    for (int ni = 0; ni < 2; ++ni)
      #pragma unroll
      for (int r = 0; r < 4; ++r)
        smf[(wr * 64 + mi * 16 + rb + r) * 68 + wc * 32 + ni * 16 + cb] = acc[mi][ni][r];
  __syncthreads();

  #pragma unroll
  for (int p = 0; p < 8; ++p) {
    const int row = p * 16 + (tid >> 4);
    const int ck  = tid & 15;
    float4 vv = *(const float4*)(smf + row * 68 + ck * 4);
    *(float4*)(out + (size_t)(m0 + row) * DMODEL + n0 + ck * 4) = vv;
  }
}

extern "C" void kernel_launch(void* const* d_in, const int* in_sizes, int n_in,
                              void* d_out, int out_size, void* d_ws, size_t ws_size,
                              hipStream_t stream) {
  (void)in_sizes; (void)n_in; (void)out_size; (void)ws_size;
  const float* X    = (const float*)d_in[0];
  const int*   tpos = (const int*)d_in[1];
  const float* Wq   = (const float*)d_in[2];
  const float* Wk   = (const float*)d_in[3];
  const float* Wv   = (const float*)d_in[4];
  const float* Wo   = (const float*)d_in[5];
  float* out = (float*)d_out;

  uint8_t* ws = (uint8_t*)d_ws;
  const size_t SZ_X = (size_t)MTOT * DMODEL * 2;      // 8 MB
  const size_t SZ_W = (size_t)DMODEL * DMODEL * 2;    // 2 MB
  const size_t SZ_H = (size_t)BB * NH * SS * DKH * 2; // 8 MB
  unsigned short* Xb   = (unsigned short*)(ws);
  unsigned short* Wqb  = (unsigned short*)(ws + SZ_X);         // [Wq;Wk;Wv;Wo]
  unsigned short* Wob  = (unsigned short*)(ws + SZ_X + 3 * SZ_W);
  unsigned short* Qh   = (unsigned short*)(ws + SZ_X + 4 * SZ_W);
  unsigned short* Kh   = (unsigned short*)(ws + SZ_X + 4 * SZ_W + SZ_H);
  unsigned short* Vt   = (unsigned short*)(ws + SZ_X + 4 * SZ_W + 2 * SZ_H);
  unsigned short* comb = Xb;  // Xb dead after QKV projection

  cvt_bf16<<<dim3(MTOT * DMODEL / 8 / 256), dim3(256), 0, stream>>>(X, Xb, MTOT * DMODEL / 8);
  cvt_w4<<<dim3(DMODEL * DMODEL / 8 / 256, 4), dim3(256), 0, stream>>>(Wq, Wk, Wv, Wo, Wqb);

  gemm_qkv<<<dim3(MTOT / BM, 24), dim3(256), 0, stream>>>(Xb, Wqb, tpos, Qh, Kh, Vt);
  attn<<<dim3(1024), dim3(256), 0, stream>>>(Qh, Kh, Vt, comb);
  gemm_out<<<dim3(MTOT / BM, 16), dim3(256), 0, stream>>>(comb, Wob, out);
}